// Round 6
// baseline (1230.337 us; speedup 1.0000x reference)
//
#include <hip/hip_runtime.h>
#include <cstdint>
#include <cstddef>

#define DEVI static __device__ __forceinline__

typedef unsigned short ushort_t;
typedef __attribute__((ext_vector_type(8))) short short8;
typedef __attribute__((ext_vector_type(4))) float f32x4;

DEVI float sp_softplus(float x) { return x > 20.f ? x : log1pf(__expf(x)); }
DEVI float silu_f(float x)      { return x / (1.f + __expf(-x)); }

DEVI ushort_t f2b(float v) {
    uint32_t u = __builtin_bit_cast(uint32_t, v);
    u += 0x7FFFu + ((u >> 16) & 1u);
    return (ushort_t)(u >> 16);
}
DEVI float b2f(ushort_t u) {
    uint32_t x = ((uint32_t)u) << 16;
    return __builtin_bit_cast(float, x);
}

DEVI void gload16(const ushort_t* g, ushort_t* l) {
    __builtin_amdgcn_global_load_lds(
        (const __attribute__((address_space(1))) unsigned int*)g,
        (__attribute__((address_space(3))) unsigned int*)l, 16, 0, 0);
}

#define NC 8
#define CL 125

// ---------------- LayerNorm: one wave per row of 512 ----------------
template<bool RELU, bool OUTB16>
__global__ __launch_bounds__(256) void ln_k(const float* __restrict__ x,
                                            const float* __restrict__ g,
                                            const float* __restrict__ b,
                                            void* __restrict__ yv, int M)
{
    int wid  = threadIdx.x >> 6;
    int lane = threadIdx.x & 63;
    int row  = blockIdx.x * 4 + wid;
    if (row >= M) return;
    const float* xr = x + (size_t)row * 512;
    float4 v0 = *(const float4*)(xr + lane * 8);
    float4 v1 = *(const float4*)(xr + lane * 8 + 4);
    float vals[8] = {v0.x, v0.y, v0.z, v0.w, v1.x, v1.y, v1.z, v1.w};
    float s = 0.f;
#pragma unroll
    for (int i = 0; i < 8; i++) s += vals[i];
#pragma unroll
    for (int off = 1; off < 64; off <<= 1) s += __shfl_xor(s, off);
    float mu = s * (1.f / 512.f);
    float q = 0.f;
#pragma unroll
    for (int i = 0; i < 8; i++) { float d = vals[i] - mu; q += d * d; }
#pragma unroll
    for (int off = 1; off < 64; off <<= 1) q += __shfl_xor(q, off);
    float rstd = rsqrtf(q * (1.f / 512.f) + 1e-5f);
#pragma unroll
    for (int i = 0; i < 8; i++) {
        int c = lane * 8 + i;
        float o = (vals[i] - mu) * rstd * g[c] + b[c];
        if (RELU) o = fmaxf(o, 0.f);
        if (OUTB16) ((ushort_t*)yv)[(size_t)row * 512 + c] = f2b(o);
        else        ((float*)yv)[(size_t)row * 512 + c] = o;
    }
}

// ---------------- converters ----------------
__global__ __launch_bounds__(256) void cvt_x_k(const float* __restrict__ x,
                                               ushort_t* __restrict__ xb)
{
    int e = blockIdx.x * 256 + threadIdx.x;
    if (e >= 2000 * 288) return;
    int k = e % 288, row = e / 288;
    xb[e] = (k < 257) ? f2b(x[(size_t)row * 257 + k]) : (ushort_t)0;
}

// small weight reshapes: conv4 w -> [4][1024], dc w -> [31][512], W_xproj -> bf16
__global__ __launch_bounds__(256) void prep_small_k(const float* __restrict__ conv_w,
                                                    const float* __restrict__ dc_w,
                                                    const float* __restrict__ W_xproj,
                                                    float* __restrict__ cwt,
                                                    float* __restrict__ dcwt,
                                                    ushort_t* __restrict__ wxb)
{
    int e = blockIdx.x * 256 + threadIdx.x;
    if (e < 16384) {
        int l = e >> 12, rem = e & 4095, k = rem >> 10, d = rem & 1023;
        cwt[e] = conv_w[l * 4096 + d * 4 + k];
        return;
    }
    e -= 16384;
    if (e < 63488) {
        int l = e / 15872, rem = e % 15872, k = rem / 512, m = rem % 512;
        dcwt[e] = dc_w[l * 15872 + m * 31 + k];
        return;
    }
    e -= 63488;
    if (e < 262144) wxb[e] = f2b(W_xproj[e]);
}

// transpose+convert: src f32 [K][N] (ld srcld) -> dst bf16 [N][ldo], zero-pad k>=Ktrue
__global__ __launch_bounds__(256) void tr_w_k(const float* __restrict__ src,
                                              ushort_t* __restrict__ dst,
                                              int Ktrue, int N, int ldo, int srcld,
                                              size_t sstride, size_t dstride)
{
    __shared__ float tile[32][33];
    src += blockIdx.z * sstride;
    dst += blockIdx.z * dstride;
    int n0 = blockIdx.x * 32, k0 = blockIdx.y * 32;
    int tx = threadIdx.x & 31, ty = threadIdx.x >> 5;
#pragma unroll
    for (int r = 0; r < 4; r++) {
        int k = k0 + ty + r * 8, n = n0 + tx;
        tile[ty + r * 8][tx] = (k < Ktrue && n < N) ? src[(size_t)k * srcld + n] : 0.f;
    }
    __syncthreads();
#pragma unroll
    for (int r = 0; r < 4; r++) {
        int n = n0 + ty + r * 8;
        if (n < N) dst[(size_t)n * ldo + k0 + tx] = f2b(tile[tx][ty + r * 8]);
    }
}

// ---------------- bf16 MFMA GEMM, 2-phase prefetch double-buffer ----------------
// A: bf16 [M][lda] (K contig). Bt: bf16 [N][ldb] (K contig). 4 waves in 2x2.
// Each wave owns (BM/2)x(BN/2). K % BK == 0. M-edge: A over-reads (buffers padded
// to 2048 rows); C stores bounds-checked. N-edge: B rows must be allocated.
// ACT: 0 none, 1 softplus(+bias), 2 split dt/proj epilogue.
template<int BM, int BN, int BK, bool BIAS, int ACT, bool RES, bool OUTF32, bool OUTB16>
__global__ __launch_bounds__(256) void gemm2(
    const ushort_t* __restrict__ A, int lda,
    const ushort_t* __restrict__ Bt, int ldb,
    const float* __restrict__ bias,
    const float* __restrict__ R, int ldr,
    float* __restrict__ C, int ldc,
    ushort_t* __restrict__ C2, int ldc2,
    int M, int N, int K,
    size_t aStr, size_t bStr, size_t cStr)
{
    const int MF = (BM / 2) / 16, NF = (BN / 2) / 16;
    const int KS = BK / 32;
    __shared__ ushort_t As[2][(BK / 8) * BM * 8];
    __shared__ ushort_t Bs[2][(BK / 8) * BN * 8];
    A  += blockIdx.z * aStr;
    Bt += blockIdx.z * bStr;
    C  += blockIdx.z * cStr;
    C2 += blockIdx.z * cStr;

    int tid = threadIdx.x;
    int wid = tid >> 6, l = tid & 63;
    int wr = wid >> 1, wc = wid & 1;
    int lk = l >> 4, lr = l & 15;

    // bijective XCD swizzle (all launch grids have nwg % 8 == 0)
    int nwg = gridDim.x * gridDim.y;
    int bid = blockIdx.y * gridDim.x + blockIdx.x;
    if ((nwg & 7) == 0) bid = (bid & 7) * (nwg >> 3) + (bid >> 3);
    int bx = bid % gridDim.x, by = bid / gridDim.x;
    int bm = by * BM, bn = bx * BN;

    f32x4 acc[MF][NF];
#pragma unroll
    for (int m = 0; m < MF; m++)
#pragma unroll
        for (int n = 0; n < NF; n++) acc[m][n] = (f32x4){0.f, 0.f, 0.f, 0.f};

    auto stage = [&](int buf, int k0) {
#pragma unroll
        for (int i = 0; i < (BM * BK / 8) / 256; i++) {
            int lin = i * 256 + tid;
            int kb = lin / BM, row = lin % BM;
            gload16(A + (size_t)(bm + row) * lda + k0 + kb * 8,
                    &As[buf][((size_t)kb * BM + row) * 8]);
        }
#pragma unroll
        for (int i = 0; i < (BN * BK / 8) / 256; i++) {
            int lin = i * 256 + tid;
            int kb = lin / BN, row = lin % BN;
            gload16(Bt + (size_t)(bn + row) * ldb + k0 + kb * 8,
                    &Bs[buf][((size_t)kb * BN + row) * 8]);
        }
    };

    auto compute = [&](int buf) {
#pragma unroll
        for (int kk = 0; kk < KS; kk++) {
            short8 af[MF], bf[NF];
#pragma unroll
            for (int m = 0; m < MF; m++) {
                int row = wr * (BM / 2) + m * 16 + lr;
                af[m] = *(const short8*)&As[buf][((size_t)(kk * 4 + lk) * BM + row) * 8];
            }
#pragma unroll
            for (int n = 0; n < NF; n++) {
                int col = wc * (BN / 2) + n * 16 + lr;
                bf[n] = *(const short8*)&Bs[buf][((size_t)(kk * 4 + lk) * BN + col) * 8];
            }
#pragma unroll
            for (int m = 0; m < MF; m++)
#pragma unroll
                for (int n = 0; n < NF; n++)
                    acc[m][n] = __builtin_amdgcn_mfma_f32_16x16x32_bf16(
                        af[m], bf[n], acc[m][n], 0, 0, 0);
        }
    };

    int nt = K / BK;
    stage(0, 0);
    asm volatile("s_waitcnt vmcnt(0)" ::: "memory");
    __syncthreads();
    int cur = 0;
    for (int t = 0; t < nt - 1; t++) {
        stage(cur ^ 1, (t + 1) * BK);
        compute(cur);
        asm volatile("s_waitcnt vmcnt(0)" ::: "memory");
        __syncthreads();
        cur ^= 1;
    }
    compute(cur);

    // epilogue: C/D layout col = lane&15, row = (lane>>4)*4 + r
#pragma unroll
    for (int m = 0; m < MF; m++) {
#pragma unroll
        for (int n = 0; n < NF; n++) {
            int gn = bn + wc * (BN / 2) + n * 16 + lr;
            if (gn >= N) continue;
#pragma unroll
            for (int r = 0; r < 4; r++) {
                int gm = bm + wr * (BM / 2) + m * 16 + lk * 4 + r;
                if (gm >= M) continue;
                float v = acc[m][n][r];
                if (ACT == 2) {
                    if (gn < 1024) C[(size_t)gm * ldc + gn] = sp_softplus(v + bias[gn]);
                    else ((float*)R)[(size_t)gm * ldr + (gn - 1024) + 32] = v;
                    continue;
                }
                if (BIAS) v += bias[gn];
                if (ACT == 1) v = sp_softplus(v);
                if (RES) v += R[(size_t)gm * ldr + gn];
                if (OUTF32) C[(size_t)gm * ldc + gn] = v;
                if (OUTB16) C2[(size_t)gm * ldc2 + gn] = f2b(v);
            }
        }
    }
}

// ---------------- causal depthwise conv (K=4) + SiLU ----------------
__global__ __launch_bounds__(256) void conv4_silu_k(const ushort_t* __restrict__ xzb,
                                                    const float* __restrict__ cwt,
                                                    const float* __restrict__ bias,
                                                    float* __restrict__ xin,
                                                    ushort_t* __restrict__ xinb)
{
    int e = blockIdx.x * 256 + threadIdx.x;
    if (e >= 2000 * 1024) return;
    int d = e & 1023;
    int row = e >> 10;
    int b = row >= 1000 ? 1 : 0;
    int t = row - b * 1000;
    float acc = bias[d];
#pragma unroll
    for (int k = 0; k < 4; k++) {
        int tt = t - 3 + k;
        if (tt >= 0) acc += b2f(xzb[((size_t)(b * 1000 + tt)) * 2048 + d]) * cwt[k * 1024 + d];
    }
    float v = silu_f(acc);
    xin[(size_t)row * 1024 + d] = v;
    xinb[(size_t)row * 1024 + d] = f2b(v);
}

// ---------------- chunked selective scan ----------------
__global__ __launch_bounds__(256) void scan_part1(const float* __restrict__ dt,
                                                  const float* __restrict__ xin,
                                                  const float* __restrict__ proj,
                                                  const float* __restrict__ A_log,
                                                  float* __restrict__ hloc,
                                                  float* __restrict__ sc)
{
    __shared__ float s_dt[CL][16], s_x[CL][16], s_B[CL][16];
    int d0 = blockIdx.x * 16;
    int c  = blockIdx.y;
    int b  = blockIdx.z;
    int tid = threadIdx.x;
    int ch = tid >> 4, st = tid & 15;
    int d = d0 + ch;
    float a_s = -__expf(A_log[d * 16 + st]);
    int base = b * 1000 + c * CL;
    for (int lin = tid; lin < CL * 16; lin += 256) {
        int tt = lin >> 4, j = lin & 15;
        size_t row = (size_t)(base + tt);
        s_dt[tt][j] = dt[row * 1024 + d0 + j];
        s_x[tt][j]  = xin[row * 1024 + d0 + j];
        s_B[tt][j]  = proj[row * 64 + 32 + j];
    }
    __syncthreads();
    float h = 0.f, sdt = 0.f;
    for (int t0 = 0; t0 < CL; t0 += 5) {
        float dA[5], du[5];
#pragma unroll
        for (int u = 0; u < 5; u++) {
            float dtv = s_dt[t0 + u][ch];
            dA[u] = __expf(dtv * a_s);
            du[u] = dtv * s_x[t0 + u][ch] * s_B[t0 + u][st];
            sdt += dtv;
        }
#pragma unroll
        for (int u = 0; u < 5; u++) h = dA[u] * h + du[u];
    }
    hloc[((size_t)(b * NC + c) << 14) + ((size_t)d << 4) + st] = h;
    if (st == 0) sc[(b * NC + c) * 1024 + d] = sdt;
}

__global__ __launch_bounds__(256) void scan_combine(const float* __restrict__ A_log,
                                                    float* __restrict__ hloc,
                                                    const float* __restrict__ sc)
{
    int e = blockIdx.x * 256 + threadIdx.x;
    if (e >= 2 * 16384) return;
    int b = e >> 14;
    int rem = e & 16383;
    int dd = rem >> 4;
    float a_s = -__expf(A_log[rem]);
    float H = hloc[((size_t)(b * NC) << 14) + rem];
    for (int c = 1; c < NC; c++) {
        size_t idx = ((size_t)(b * NC + c) << 14) + rem;
        H = hloc[idx] + __expf(a_s * sc[(b * NC + c) * 1024 + dd]) * H;
        hloc[idx] = H;
    }
}

// part2 + fused gating: writes ysb = bf16((y + xin*Dp) * silu(z))
__global__ __launch_bounds__(256) void scan_part2(const float* __restrict__ dt,
                                                  const float* __restrict__ xin,
                                                  const float* __restrict__ proj,
                                                  const float* __restrict__ A_log,
                                                  const float* __restrict__ hend,
                                                  const float* __restrict__ Dp,
                                                  const ushort_t* __restrict__ xzb,
                                                  ushort_t* __restrict__ ysb)
{
    __shared__ float s_dt[CL][16], s_x[CL][16], s_B[CL][16], s_C[CL][16], s_y[CL][16];
    int d0 = blockIdx.x * 16;
    int c  = blockIdx.y;
    int b  = blockIdx.z;
    int tid = threadIdx.x;
    int ch = tid >> 4, st = tid & 15;
    int d = d0 + ch;
    float a_s = -__expf(A_log[d * 16 + st]);
    int base = b * 1000 + c * CL;
    for (int lin = tid; lin < CL * 16; lin += 256) {
        int tt = lin >> 4, j = lin & 15;
        size_t row = (size_t)(base + tt);
        s_dt[tt][j] = dt[row * 1024 + d0 + j];
        s_x[tt][j]  = xin[row * 1024 + d0 + j];
        s_B[tt][j]  = proj[row * 64 + 32 + j];
        s_C[tt][j]  = proj[row * 64 + 48 + j];
    }
    float h = 0.f;
    if (c > 0) h = hend[((size_t)(b * NC + c - 1) << 14) + ((size_t)d << 4) + st];
    __syncthreads();
    for (int t0 = 0; t0 < CL; t0 += 5) {
        float dA[5], du[5], p[5];
#pragma unroll
        for (int u = 0; u < 5; u++) {
            float dtv = s_dt[t0 + u][ch];
            dA[u] = __expf(dtv * a_s);
            du[u] = dtv * s_x[t0 + u][ch] * s_B[t0 + u][st];
        }
#pragma unroll
        for (int u = 0; u < 5; u++) {
            h = dA[u] * h + du[u];
            p[u] = h * s_C[t0 + u][st];
        }
#pragma unroll
        for (int u = 0; u < 5; u++) {
            p[u] += __shfl_xor(p[u], 1);
            p[u] += __shfl_xor(p[u], 2);
            p[u] += __shfl_xor(p[u], 4);
            p[u] += __shfl_xor(p[u], 8);
            if (st == 0) s_y[t0 + u][ch] = p[u];
        }
    }
    __syncthreads();
    for (int lin = tid; lin < CL * 16; lin += 256) {
        int tt = lin >> 4, j = lin & 15;
        size_t row = (size_t)(base + tt);
        float z = b2f(xzb[row * 2048 + 1024 + d0 + j]);
        float yv = (s_y[tt][j] + s_x[tt][j] * Dp[d0 + j]) * silu_f(z);
        ysb[row * 1024 + d0 + j] = f2b(yv);
    }
}

// ---------------- depthwise conv31 + residual (coalesced weights) ----------------
__global__ __launch_bounds__(256) void dcconv31_k(const float* __restrict__ ln,
                                                  const float* __restrict__ a,
                                                  const float* __restrict__ dcwt,
                                                  const float* __restrict__ bias,
                                                  float* __restrict__ h,
                                                  ushort_t* __restrict__ hb)
{
    int e = blockIdx.x * 256 + threadIdx.x;
    if (e >= 2000 * 512) return;
    int m = e & 511;
    int row = e >> 9;
    int b = row >= 1000 ? 1 : 0;
    int t = row - b * 1000;
    float acc = bias[m];
#pragma unroll
    for (int k = 0; k < 31; k++) {
        int tt = t - 15 + k;
        if (tt >= 0 && tt < 1000)
            acc += ln[((size_t)(b * 1000 + tt)) * 512 + m] * dcwt[k * 512 + m];
    }
    float v = a[e] + acc;
    h[e] = v;
    hb[e] = f2b(v);
}

// ---------------- seq_mask output ----------------
__global__ void mask_k(const int* __restrict__ lengths, float* __restrict__ out)
{
    int i = blockIdx.x * 256 + threadIdx.x;
    if (i >= 2000) return;
    out[i] = ((i % 1000) < lengths[i / 1000]) ? 1.f : 0.f;
}

extern "C" void kernel_launch(void* const* d_in, const int* in_sizes, int n_in,
                              void* d_out, int out_size, void* d_ws, size_t ws_size,
                              hipStream_t stream)
{
    const float* x       = (const float*)d_in[0];
    const int*   lengths = (const int*)  d_in[1];
    const float* w_in0   = (const float*)d_in[2];
    const float* ln_in_g = (const float*)d_in[3];
    const float* ln_in_b = (const float*)d_in[4];
    const float* ln1_g   = (const float*)d_in[5];
    const float* ln1_b   = (const float*)d_in[6];
    const float* W_inproj= (const float*)d_in[7];
    const float* conv_w  = (const float*)d_in[8];
    const float* conv_b  = (const float*)d_in[9];
    const float* W_xproj = (const float*)d_in[10];
    const float* W_dt    = (const float*)d_in[11];
    const float* b_dt    = (const float*)d_in[12];
    const float* A_log   = (const float*)d_in[13];
    const float* Dp      = (const float*)d_in[14];
    const float* W_mo    = (const float*)d_in[15];
    const float* ln2_g   = (const float*)d_in[16];
    const float* ln2_b   = (const float*)d_in[17];
    const float* dc_w    = (const float*)d_in[18];
    const float* dc_b    = (const float*)d_in[19];
    const float* w_out   = (const float*)d_in[20];
    const float* b_out   = (const float*)d_in[21];

    char* p = (char*)d_ws;
    auto alloc_f = [&](size_t n) { float* r = (float*)p; p += n * 4; return r; };
    auto alloc_b = [&](size_t n) { ushort_t* r = (ushort_t*)p; p += n * 2; return r; };

    float* h    = alloc_f(2048 * 512);
    float* lnb  = alloc_f(2048 * 512);
    float* xin  = alloc_f(2048 * 1024);
    float* proj = alloc_f(2048 * 64);
    float* dtb  = alloc_f(2048 * 1024);
    float* av   = alloc_f(2048 * 512);
    float* hloc = alloc_f(262144);
    float* sc   = alloc_f(16384);
    float* cwt  = alloc_f(4 * 4 * 1024);
    float* dcwt = alloc_f(4 * 31 * 512);
    ushort_t* xbf   = alloc_b(2048 * 288);
    ushort_t* lnbb  = alloc_b(2048 * 512);
    ushort_t* xzb   = alloc_b(2048 * 2048);
    ushort_t* xinb  = alloc_b(2048 * 1024);
    ushort_t* ysb   = alloc_b(2048 * 1024);
    ushort_t* hb    = alloc_b(2048 * 512);
    ushort_t* wt_in0 = alloc_b(512 * 288);
    ushort_t* wt_in  = alloc_b((size_t)4 * 2048 * 512);
    ushort_t* wt_dt  = alloc_b((size_t)4 * 1024 * 32);
    ushort_t* wt_mo  = alloc_b((size_t)4 * 512 * 1024);
    ushort_t* wt_out = alloc_b(576 * 512);
    ushort_t* wxb    = alloc_b((size_t)4 * 1024 * 64);
    ushort_t* wt_big = alloc_b((size_t)4 * 1152 * 1024);

    dim3 blk(256);

    // ---- weight prep ----
    cvt_x_k<<<(2000 * 288 + 255) / 256, blk, 0, stream>>>(x, xbf);
    prep_small_k<<<(16384 + 63488 + 262144 + 255) / 256, blk, 0, stream>>>(
        conv_w, dc_w, W_xproj, cwt, dcwt, wxb);
    tr_w_k<<<dim3(16, 9, 1),  blk, 0, stream>>>(w_in0, wt_in0, 257, 512, 288, 512, 0, 0);
    tr_w_k<<<dim3(64, 16, 4), blk, 0, stream>>>(W_inproj, wt_in, 512, 2048, 512, 2048,
                                                (size_t)512 * 2048, (size_t)2048 * 512);
    tr_w_k<<<dim3(32, 1, 4),  blk, 0, stream>>>(W_dt, wt_dt, 32, 1024, 32, 1024,
                                                (size_t)32 * 1024, (size_t)1024 * 32);
    tr_w_k<<<dim3(16, 32, 4), blk, 0, stream>>>(W_mo, wt_mo, 1024, 512, 1024, 512,
                                                (size_t)1024 * 512, (size_t)512 * 1024);
    tr_w_k<<<dim3(17, 16, 1), blk, 0, stream>>>(w_out, wt_out, 512, 514, 512, 514, 0, 0);
    // W_x[:,32:64] transposed into wt_big rows 1024..1055
    tr_w_k<<<dim3(1, 32, 4),  blk, 0, stream>>>(W_xproj + 32, wt_big + (size_t)1024 * 1024,
                                                1024, 32, 1024, 64,
                                                (size_t)1024 * 64, (size_t)1152 * 1024);
    // W_comb (batched over 4 layers): wt_big[j][k] = sum_r W_dt[r][j] * W_x[k][r]
    gemm2<128, 128, 32, false, 0, false, false, true><<<dim3(8, 8, 4), blk, 0, stream>>>(
        wt_dt, 32, wxb, 64, nullptr, nullptr, 0, nullptr, 0, wt_big, 1024,
        1024, 1024, 32,
        (size_t)1024 * 32, (size_t)1024 * 64, (size_t)1152 * 1024);

    // ---- input projection + LN/relu ----
    gemm2<128, 64, 32, false, 0, false, true, false><<<dim3(8, 16), blk, 0, stream>>>(
        xbf, 288, wt_in0, 288, nullptr, nullptr, 0, lnb, 512, nullptr, 0,
        2000, 512, 288, 0, 0, 0);
    ln_k<true, false><<<500, blk, 0, stream>>>(lnb, ln_in_g, ln_in_b, h, 2000);

    for (int i = 0; i < 4; i++) {
        const float* Al = A_log + (size_t)i * 16384;
        ln_k<false, true><<<500, blk, 0, stream>>>(h, ln1_g + i * 512, ln1_b + i * 512,
                                                   lnbb, 2000);
        gemm2<128, 128, 64, false, 0, false, false, true><<<dim3(16, 16), blk, 0, stream>>>(
            lnbb, 512, wt_in + (size_t)i * 2048 * 512, 512,
            nullptr, nullptr, 0, nullptr, 0, xzb, 2048, 2000, 2048, 512, 0, 0, 0);
        conv4_silu_k<<<8000, blk, 0, stream>>>(xzb, cwt + i * 4096,
                                               conv_b + i * 1024, xin, xinb);
        // fused xproj+dt: N=1056 (1024 dt | 32 B,C)
        gemm2<128, 128, 64, false, 2, false, false, false><<<dim3(9, 16), blk, 0, stream>>>(
            xinb, 1024, wt_big + (size_t)i * 1152 * 1024, 1024,
            b_dt + i * 1024, proj, 64, dtb, 1024, nullptr, 0, 2000, 1056, 1024, 0, 0, 0);
        scan_part1<<<dim3(64, NC, 2), blk, 0, stream>>>(dtb, xin, proj, Al, hloc, sc);
        scan_combine<<<128, blk, 0, stream>>>(Al, hloc, sc);
        scan_part2<<<dim3(64, NC, 2), blk, 0, stream>>>(dtb, xin, proj, Al, hloc,
                                                        Dp + i * 1024, xzb, ysb);
        gemm2<128, 64, 64, false, 0, true, true, false><<<dim3(8, 16), blk, 0, stream>>>(
            ysb, 1024, wt_mo + (size_t)i * 512 * 1024, 1024,
            nullptr, h, 512, av, 512, nullptr, 0, 2000, 512, 1024, 0, 0, 0);
        ln_k<false, false><<<500, blk, 0, stream>>>(av, ln2_g + i * 512, ln2_b + i * 512,
                                                    lnb, 2000);
        dcconv31_k<<<4000, blk, 0, stream>>>(lnb, av, dcwt + i * 31 * 512,
                                             dc_b + i * 512, h, hb);
    }

    gemm2<128, 64, 64, true, 0, false, true, false><<<dim3(9, 16), blk, 0, stream>>>(
        hb, 512, wt_out, 512, b_out, nullptr, 0, (float*)d_out, 514, nullptr, 0,
        2000, 514, 512, 0, 0, 0);
    mask_k<<<8, blk, 0, stream>>>(lengths, (float*)d_out + 2000 * 514);
}

// Round 7
// 755.339 us; speedup vs baseline: 1.6289x; 1.6289x over previous
//
#include <hip/hip_runtime.h>
#include <cstdint>
#include <cstddef>

#define DEVI static __device__ __forceinline__

typedef unsigned short ushort_t;
typedef __attribute__((ext_vector_type(8))) short short8;
typedef __attribute__((ext_vector_type(4))) float f32x4;

DEVI float sp_softplus(float x) { return x > 20.f ? x : log1pf(__expf(x)); }
DEVI float silu_f(float x)      { return x / (1.f + __expf(-x)); }

DEVI ushort_t f2b(float v) {
    uint32_t u = __builtin_bit_cast(uint32_t, v);
    u += 0x7FFFu + ((u >> 16) & 1u);
    return (ushort_t)(u >> 16);
}
DEVI float b2f(ushort_t u) {
    uint32_t x = ((uint32_t)u) << 16;
    return __builtin_bit_cast(float, x);
}

DEVI void gload16(const ushort_t* g, ushort_t* l) {
    __builtin_amdgcn_global_load_lds(
        (const __attribute__((address_space(1))) unsigned int*)g,
        (__attribute__((address_space(3))) unsigned int*)l, 16, 0, 0);
}

#define NC 8
#define CL 125

// ---------------- LayerNorm: one wave per row of 512 ----------------
template<bool RELU, bool OUTB16>
__global__ __launch_bounds__(256) void ln_k(const float* __restrict__ x,
                                            const float* __restrict__ g,
                                            const float* __restrict__ b,
                                            void* __restrict__ yv, int M)
{
    int wid  = threadIdx.x >> 6;
    int lane = threadIdx.x & 63;
    int row  = blockIdx.x * 4 + wid;
    if (row >= M) return;
    const float* xr = x + (size_t)row * 512;
    float4 v0 = *(const float4*)(xr + lane * 8);
    float4 v1 = *(const float4*)(xr + lane * 8 + 4);
    float vals[8] = {v0.x, v0.y, v0.z, v0.w, v1.x, v1.y, v1.z, v1.w};
    float s = 0.f;
#pragma unroll
    for (int i = 0; i < 8; i++) s += vals[i];
#pragma unroll
    for (int off = 1; off < 64; off <<= 1) s += __shfl_xor(s, off);
    float mu = s * (1.f / 512.f);
    float q = 0.f;
#pragma unroll
    for (int i = 0; i < 8; i++) { float d = vals[i] - mu; q += d * d; }
#pragma unroll
    for (int off = 1; off < 64; off <<= 1) q += __shfl_xor(q, off);
    float rstd = rsqrtf(q * (1.f / 512.f) + 1e-5f);
#pragma unroll
    for (int i = 0; i < 8; i++) {
        int c = lane * 8 + i;
        float o = (vals[i] - mu) * rstd * g[c] + b[c];
        if (RELU) o = fmaxf(o, 0.f);
        if (OUTB16) ((ushort_t*)yv)[(size_t)row * 512 + c] = f2b(o);
        else        ((float*)yv)[(size_t)row * 512 + c] = o;
    }
}

// ---------------- converters ----------------
__global__ __launch_bounds__(256) void cvt_x_k(const float* __restrict__ x,
                                               ushort_t* __restrict__ xb)
{
    int e = blockIdx.x * 256 + threadIdx.x;
    if (e >= 2000 * 288) return;
    int k = e % 288, row = e / 288;
    xb[e] = (k < 257) ? f2b(x[(size_t)row * 257 + k]) : (ushort_t)0;
}

// small weight reshapes: conv4 w -> [4][1024], dc w -> [31][512], W_xproj -> bf16
__global__ __launch_bounds__(256) void prep_small_k(const float* __restrict__ conv_w,
                                                    const float* __restrict__ dc_w,
                                                    const float* __restrict__ W_xproj,
                                                    float* __restrict__ cwt,
                                                    float* __restrict__ dcwt,
                                                    ushort_t* __restrict__ wxb)
{
    int e = blockIdx.x * 256 + threadIdx.x;
    if (e < 16384) {
        int l = e >> 12, rem = e & 4095, k = rem >> 10, d = rem & 1023;
        cwt[e] = conv_w[l * 4096 + d * 4 + k];
        return;
    }
    e -= 16384;
    if (e < 63488) {
        int l = e / 15872, rem = e % 15872, k = rem / 512, m = rem % 512;
        dcwt[e] = dc_w[l * 15872 + m * 31 + k];
        return;
    }
    e -= 63488;
    if (e < 262144) wxb[e] = f2b(W_xproj[e]);
}

// transpose+convert: src f32 [K][N] (ld srcld) -> dst bf16 [N][ldo], zero-pad k>=Ktrue
__global__ __launch_bounds__(256) void tr_w_k(const float* __restrict__ src,
                                              ushort_t* __restrict__ dst,
                                              int Ktrue, int N, int ldo, int srcld,
                                              size_t sstride, size_t dstride)
{
    __shared__ float tile[32][33];
    src += blockIdx.z * sstride;
    dst += blockIdx.z * dstride;
    int n0 = blockIdx.x * 32, k0 = blockIdx.y * 32;
    int tx = threadIdx.x & 31, ty = threadIdx.x >> 5;
#pragma unroll
    for (int r = 0; r < 4; r++) {
        int k = k0 + ty + r * 8, n = n0 + tx;
        tile[ty + r * 8][tx] = (k < Ktrue && n < N) ? src[(size_t)k * srcld + n] : 0.f;
    }
    __syncthreads();
#pragma unroll
    for (int r = 0; r < 4; r++) {
        int n = n0 + ty + r * 8;
        if (n < N) dst[(size_t)n * ldo + k0 + tx] = f2b(tile[tx][ty + r * 8]);
    }
}

// ---------------- bf16 MFMA GEMM: 64x64 tile, BK=32, double-buffered LDS ----------------
// A: bf16 [M][lda] (K contig). Bt: bf16 [N][ldb] (K contig). 4 waves in 2x2,
// each wave owns 32x32. K % 32 == 0. A/B buffers must have ceil rows allocated;
// C stores bounds-checked. Small LDS (16KB) -> high blocks/CU (occupancy-first).
// ACT: 0 none, 1 softplus(+bias), 2 split dt/proj epilogue.
template<bool BIAS, int ACT, bool RES, bool OUTF32, bool OUTB16>
__global__ __launch_bounds__(256) void gemm3(
    const ushort_t* __restrict__ A, int lda,
    const ushort_t* __restrict__ Bt, int ldb,
    const float* __restrict__ bias,
    const float* __restrict__ R, int ldr,
    float* __restrict__ C, int ldc,
    ushort_t* __restrict__ C2, int ldc2,
    int M, int N, int K,
    size_t aStr, size_t bStr, size_t cStr)
{
    __shared__ ushort_t As[2][4 * 64 * 8];
    __shared__ ushort_t Bs[2][4 * 64 * 8];
    A  += blockIdx.z * aStr;
    Bt += blockIdx.z * bStr;
    C  += blockIdx.z * cStr;
    C2 += blockIdx.z * cStr;

    int tid = threadIdx.x;
    int wid = tid >> 6, l = tid & 63;
    int wr = wid >> 1, wc = wid & 1;
    int lk = l >> 4, lr = l & 15;
    int bm = blockIdx.y * 64, bn = blockIdx.x * 64;

    f32x4 acc[2][2];
#pragma unroll
    for (int m = 0; m < 2; m++)
#pragma unroll
        for (int n = 0; n < 2; n++) acc[m][n] = (f32x4){0.f, 0.f, 0.f, 0.f};

    // stage one BK=32 tile: kb = wid (k-subtile of 8), row = l
    auto stage = [&](int buf, int k0) {
        gload16(A  + (size_t)(bm + l) * lda + k0 + wid * 8, &As[buf][(wid * 64 + l) * 8]);
        gload16(Bt + (size_t)(bn + l) * ldb + k0 + wid * 8, &Bs[buf][(wid * 64 + l) * 8]);
    };

    auto compute = [&](int buf) {
        short8 af[2], bf[2];
#pragma unroll
        for (int m = 0; m < 2; m++) {
            int row = wr * 32 + m * 16 + lr;
            af[m] = *(const short8*)&As[buf][(lk * 64 + row) * 8];
        }
#pragma unroll
        for (int n = 0; n < 2; n++) {
            int col = wc * 32 + n * 16 + lr;
            bf[n] = *(const short8*)&Bs[buf][(lk * 64 + col) * 8];
        }
#pragma unroll
        for (int m = 0; m < 2; m++)
#pragma unroll
            for (int n = 0; n < 2; n++)
                acc[m][n] = __builtin_amdgcn_mfma_f32_16x16x32_bf16(
                    af[m], bf[n], acc[m][n], 0, 0, 0);
    };

    int nt = K >> 5;
    stage(0, 0);
    asm volatile("s_waitcnt vmcnt(0)" ::: "memory");
    __syncthreads();
    int cur = 0;
    for (int t = 0; t < nt - 1; t++) {
        stage(cur ^ 1, (t + 1) * 32);   // prefetch next while computing current
        compute(cur);
        asm volatile("s_waitcnt vmcnt(0)" ::: "memory");
        __syncthreads();
        cur ^= 1;
    }
    compute(cur);

    // epilogue: C/D layout col = lane&15, row = (lane>>4)*4 + r
#pragma unroll
    for (int m = 0; m < 2; m++) {
#pragma unroll
        for (int n = 0; n < 2; n++) {
            int gn = bn + wc * 32 + n * 16 + lr;
            if (gn >= N) continue;
#pragma unroll
            for (int r = 0; r < 4; r++) {
                int gm = bm + wr * 32 + m * 16 + lk * 4 + r;
                if (gm >= M) continue;
                float v = acc[m][n][r];
                if (ACT == 2) {
                    if (gn < 1024) C[(size_t)gm * ldc + gn] = sp_softplus(v + bias[gn]);
                    else ((float*)R)[(size_t)gm * ldr + (gn - 1024) + 32] = v;
                    continue;
                }
                if (BIAS) v += bias[gn];
                if (ACT == 1) v = sp_softplus(v);
                if (RES) v += R[(size_t)gm * ldr + gn];
                if (OUTF32) C[(size_t)gm * ldc + gn] = v;
                if (OUTB16) C2[(size_t)gm * ldc2 + gn] = f2b(v);
            }
        }
    }
}

// ---------------- causal depthwise conv (K=4) + SiLU ----------------
__global__ __launch_bounds__(256) void conv4_silu_k(const ushort_t* __restrict__ xzb,
                                                    const float* __restrict__ cwt,
                                                    const float* __restrict__ bias,
                                                    float* __restrict__ xin,
                                                    ushort_t* __restrict__ xinb)
{
    int e = blockIdx.x * 256 + threadIdx.x;
    if (e >= 2000 * 1024) return;
    int d = e & 1023;
    int row = e >> 10;
    int b = row >= 1000 ? 1 : 0;
    int t = row - b * 1000;
    float acc = bias[d];
#pragma unroll
    for (int k = 0; k < 4; k++) {
        int tt = t - 3 + k;
        if (tt >= 0) acc += b2f(xzb[((size_t)(b * 1000 + tt)) * 2048 + d]) * cwt[k * 1024 + d];
    }
    float v = silu_f(acc);
    xin[(size_t)row * 1024 + d] = v;
    xinb[(size_t)row * 1024 + d] = f2b(v);
}

// ---------------- chunked selective scan ----------------
__global__ __launch_bounds__(256) void scan_part1(const float* __restrict__ dt,
                                                  const float* __restrict__ xin,
                                                  const float* __restrict__ proj,
                                                  const float* __restrict__ A_log,
                                                  float* __restrict__ hloc,
                                                  float* __restrict__ sc)
{
    __shared__ float s_dt[CL][16], s_x[CL][16], s_B[CL][16];
    int d0 = blockIdx.x * 16;
    int c  = blockIdx.y;
    int b  = blockIdx.z;
    int tid = threadIdx.x;
    int ch = tid >> 4, st = tid & 15;
    int d = d0 + ch;
    float a_s = -__expf(A_log[d * 16 + st]);
    int base = b * 1000 + c * CL;
    for (int lin = tid; lin < CL * 16; lin += 256) {
        int tt = lin >> 4, j = lin & 15;
        size_t row = (size_t)(base + tt);
        s_dt[tt][j] = dt[row * 1024 + d0 + j];
        s_x[tt][j]  = xin[row * 1024 + d0 + j];
        s_B[tt][j]  = proj[row * 64 + 32 + j];
    }
    __syncthreads();
    float h = 0.f, sdt = 0.f;
    for (int t0 = 0; t0 < CL; t0 += 5) {
        float dA[5], du[5];
#pragma unroll
        for (int u = 0; u < 5; u++) {
            float dtv = s_dt[t0 + u][ch];
            dA[u] = __expf(dtv * a_s);
            du[u] = dtv * s_x[t0 + u][ch] * s_B[t0 + u][st];
            sdt += dtv;
        }
#pragma unroll
        for (int u = 0; u < 5; u++) h = dA[u] * h + du[u];
    }
    hloc[((size_t)(b * NC + c) << 14) + ((size_t)d << 4) + st] = h;
    if (st == 0) sc[(b * NC + c) * 1024 + d] = sdt;
}

__global__ __launch_bounds__(256) void scan_combine(const float* __restrict__ A_log,
                                                    float* __restrict__ hloc,
                                                    const float* __restrict__ sc)
{
    int e = blockIdx.x * 256 + threadIdx.x;
    if (e >= 2 * 16384) return;
    int b = e >> 14;
    int rem = e & 16383;
    int dd = rem >> 4;
    float a_s = -__expf(A_log[rem]);
    float H = hloc[((size_t)(b * NC) << 14) + rem];
    for (int c = 1; c < NC; c++) {
        size_t idx = ((size_t)(b * NC + c) << 14) + rem;
        H = hloc[idx] + __expf(a_s * sc[(b * NC + c) * 1024 + dd]) * H;
        hloc[idx] = H;
    }
}

// part2 + fused gating: writes ysb = bf16((y + xin*Dp) * silu(z))
__global__ __launch_bounds__(256) void scan_part2(const float* __restrict__ dt,
                                                  const float* __restrict__ xin,
                                                  const float* __restrict__ proj,
                                                  const float* __restrict__ A_log,
                                                  const float* __restrict__ hend,
                                                  const float* __restrict__ Dp,
                                                  const ushort_t* __restrict__ xzb,
                                                  ushort_t* __restrict__ ysb)
{
    __shared__ float s_dt[CL][16], s_x[CL][16], s_B[CL][16], s_C[CL][16], s_y[CL][16];
    int d0 = blockIdx.x * 16;
    int c  = blockIdx.y;
    int b  = blockIdx.z;
    int tid = threadIdx.x;
    int ch = tid >> 4, st = tid & 15;
    int d = d0 + ch;
    float a_s = -__expf(A_log[d * 16 + st]);
    int base = b * 1000 + c * CL;
    for (int lin = tid; lin < CL * 16; lin += 256) {
        int tt = lin >> 4, j = lin & 15;
        size_t row = (size_t)(base + tt);
        s_dt[tt][j] = dt[row * 1024 + d0 + j];
        s_x[tt][j]  = xin[row * 1024 + d0 + j];
        s_B[tt][j]  = proj[row * 64 + 32 + j];
        s_C[tt][j]  = proj[row * 64 + 48 + j];
    }
    float h = 0.f;
    if (c > 0) h = hend[((size_t)(b * NC + c - 1) << 14) + ((size_t)d << 4) + st];
    __syncthreads();
    for (int t0 = 0; t0 < CL; t0 += 5) {
        float dA[5], du[5], p[5];
#pragma unroll
        for (int u = 0; u < 5; u++) {
            float dtv = s_dt[t0 + u][ch];
            dA[u] = __expf(dtv * a_s);
            du[u] = dtv * s_x[t0 + u][ch] * s_B[t0 + u][st];
        }
#pragma unroll
        for (int u = 0; u < 5; u++) {
            h = dA[u] * h + du[u];
            p[u] = h * s_C[t0 + u][st];
        }
#pragma unroll
        for (int u = 0; u < 5; u++) {
            p[u] += __shfl_xor(p[u], 1);
            p[u] += __shfl_xor(p[u], 2);
            p[u] += __shfl_xor(p[u], 4);
            p[u] += __shfl_xor(p[u], 8);
            if (st == 0) s_y[t0 + u][ch] = p[u];
        }
    }
    __syncthreads();
    for (int lin = tid; lin < CL * 16; lin += 256) {
        int tt = lin >> 4, j = lin & 15;
        size_t row = (size_t)(base + tt);
        float z = b2f(xzb[row * 2048 + 1024 + d0 + j]);
        float yv = (s_y[tt][j] + s_x[tt][j] * Dp[d0 + j]) * silu_f(z);
        ysb[row * 1024 + d0 + j] = f2b(yv);
    }
}

// ---------------- depthwise conv31 + residual (coalesced weights) ----------------
__global__ __launch_bounds__(256) void dcconv31_k(const float* __restrict__ ln,
                                                  const float* __restrict__ a,
                                                  const float* __restrict__ dcwt,
                                                  const float* __restrict__ bias,
                                                  float* __restrict__ h,
                                                  ushort_t* __restrict__ hb)
{
    int e = blockIdx.x * 256 + threadIdx.x;
    if (e >= 2000 * 512) return;
    int m = e & 511;
    int row = e >> 9;
    int b = row >= 1000 ? 1 : 0;
    int t = row - b * 1000;
    float acc = bias[m];
#pragma unroll
    for (int k = 0; k < 31; k++) {
        int tt = t - 15 + k;
        if (tt >= 0 && tt < 1000)
            acc += ln[((size_t)(b * 1000 + tt)) * 512 + m] * dcwt[k * 512 + m];
    }
    float v = a[e] + acc;
    h[e] = v;
    hb[e] = f2b(v);
}

// ---------------- seq_mask output ----------------
__global__ void mask_k(const int* __restrict__ lengths, float* __restrict__ out)
{
    int i = blockIdx.x * 256 + threadIdx.x;
    if (i >= 2000) return;
    out[i] = ((i % 1000) < lengths[i / 1000]) ? 1.f : 0.f;
}

extern "C" void kernel_launch(void* const* d_in, const int* in_sizes, int n_in,
                              void* d_out, int out_size, void* d_ws, size_t ws_size,
                              hipStream_t stream)
{
    const float* x       = (const float*)d_in[0];
    const int*   lengths = (const int*)  d_in[1];
    const float* w_in0   = (const float*)d_in[2];
    const float* ln_in_g = (const float*)d_in[3];
    const float* ln_in_b = (const float*)d_in[4];
    const float* ln1_g   = (const float*)d_in[5];
    const float* ln1_b   = (const float*)d_in[6];
    const float* W_inproj= (const float*)d_in[7];
    const float* conv_w  = (const float*)d_in[8];
    const float* conv_b  = (const float*)d_in[9];
    const float* W_xproj = (const float*)d_in[10];
    const float* W_dt    = (const float*)d_in[11];
    const float* b_dt    = (const float*)d_in[12];
    const float* A_log   = (const float*)d_in[13];
    const float* Dp      = (const float*)d_in[14];
    const float* W_mo    = (const float*)d_in[15];
    const float* ln2_g   = (const float*)d_in[16];
    const float* ln2_b   = (const float*)d_in[17];
    const float* dc_w    = (const float*)d_in[18];
    const float* dc_b    = (const float*)d_in[19];
    const float* w_out   = (const float*)d_in[20];
    const float* b_out   = (const float*)d_in[21];

    char* p = (char*)d_ws;
    auto alloc_f = [&](size_t n) { float* r = (float*)p; p += n * 4; return r; };
    auto alloc_b = [&](size_t n) { ushort_t* r = (ushort_t*)p; p += n * 2; return r; };

    float* h    = alloc_f(2048 * 512);
    float* lnb  = alloc_f(2048 * 512);
    float* xin  = alloc_f(2048 * 1024);
    float* proj = alloc_f(2048 * 64);
    float* dtb  = alloc_f(2048 * 1024);
    float* av   = alloc_f(2048 * 512);
    float* hloc = alloc_f(262144);
    float* sc   = alloc_f(16384);
    float* cwt  = alloc_f(4 * 4 * 1024);
    float* dcwt = alloc_f(4 * 31 * 512);
    ushort_t* xbf   = alloc_b(2048 * 288);
    ushort_t* lnbb  = alloc_b(2048 * 512);
    ushort_t* xzb   = alloc_b(2048 * 2048);
    ushort_t* xinb  = alloc_b(2048 * 1024);
    ushort_t* ysb   = alloc_b(2048 * 1024);
    ushort_t* hb    = alloc_b(2048 * 512);
    ushort_t* wt_in0 = alloc_b(512 * 288);
    ushort_t* wt_in  = alloc_b((size_t)4 * 2048 * 512);
    ushort_t* wt_dt  = alloc_b((size_t)4 * 1024 * 32);
    ushort_t* wt_mo  = alloc_b((size_t)4 * 512 * 1024);
    ushort_t* wt_out = alloc_b(576 * 512);
    ushort_t* wxb    = alloc_b((size_t)4 * 1024 * 64);
    ushort_t* wt_big = alloc_b((size_t)4 * 1152 * 1024);

    dim3 blk(256);

    // ---- weight prep ----
    cvt_x_k<<<(2000 * 288 + 255) / 256, blk, 0, stream>>>(x, xbf);
    prep_small_k<<<(16384 + 63488 + 262144 + 255) / 256, blk, 0, stream>>>(
        conv_w, dc_w, W_xproj, cwt, dcwt, wxb);
    tr_w_k<<<dim3(16, 9, 1),  blk, 0, stream>>>(w_in0, wt_in0, 257, 512, 288, 512, 0, 0);
    tr_w_k<<<dim3(64, 16, 4), blk, 0, stream>>>(W_inproj, wt_in, 512, 2048, 512, 2048,
                                                (size_t)512 * 2048, (size_t)2048 * 512);
    tr_w_k<<<dim3(32, 1, 4),  blk, 0, stream>>>(W_dt, wt_dt, 32, 1024, 32, 1024,
                                                (size_t)32 * 1024, (size_t)1024 * 32);
    tr_w_k<<<dim3(16, 32, 4), blk, 0, stream>>>(W_mo, wt_mo, 1024, 512, 1024, 512,
                                                (size_t)1024 * 512, (size_t)512 * 1024);
    tr_w_k<<<dim3(17, 16, 1), blk, 0, stream>>>(w_out, wt_out, 512, 514, 512, 514, 0, 0);
    // W_x[:,32:64] transposed into wt_big rows 1024..1055
    tr_w_k<<<dim3(1, 32, 4),  blk, 0, stream>>>(W_xproj + 32, wt_big + (size_t)1024 * 1024,
                                                1024, 32, 1024, 64,
                                                (size_t)1024 * 64, (size_t)1152 * 1024);
    // W_comb (batched over 4 layers): wt_big[j][k] = sum_r W_dt[r][j] * W_x[k][r]
    gemm3<false, 0, false, false, true><<<dim3(16, 16, 4), blk, 0, stream>>>(
        wt_dt, 32, wxb, 64, nullptr, nullptr, 0, nullptr, 0, wt_big, 1024,
        1024, 1024, 32,
        (size_t)1024 * 32, (size_t)1024 * 64, (size_t)1152 * 1024);

    // ---- input projection + LN/relu ----
    gemm3<false, 0, false, true, false><<<dim3(8, 32), blk, 0, stream>>>(
        xbf, 288, wt_in0, 288, nullptr, nullptr, 0, lnb, 512, nullptr, 0,
        2000, 512, 288, 0, 0, 0);
    ln_k<true, false><<<500, blk, 0, stream>>>(lnb, ln_in_g, ln_in_b, h, 2000);

    for (int i = 0; i < 4; i++) {
        const float* Al = A_log + (size_t)i * 16384;
        ln_k<false, true><<<500, blk, 0, stream>>>(h, ln1_g + i * 512, ln1_b + i * 512,
                                                   lnbb, 2000);
        gemm3<false, 0, false, false, true><<<dim3(32, 32), blk, 0, stream>>>(
            lnbb, 512, wt_in + (size_t)i * 2048 * 512, 512,
            nullptr, nullptr, 0, nullptr, 0, xzb, 2048, 2000, 2048, 512, 0, 0, 0);
        conv4_silu_k<<<8000, blk, 0, stream>>>(xzb, cwt + i * 4096,
                                               conv_b + i * 1024, xin, xinb);
        // fused xproj+dt: N=1056 (1024 dt | 32 B,C)
        gemm3<false, 2, false, false, false><<<dim3(17, 32), blk, 0, stream>>>(
            xinb, 1024, wt_big + (size_t)i * 1152 * 1024, 1024,
            b_dt + i * 1024, proj, 64, dtb, 1024, nullptr, 0, 2000, 1056, 1024, 0, 0, 0);
        scan_part1<<<dim3(64, NC, 2), blk, 0, stream>>>(dtb, xin, proj, Al, hloc, sc);
        scan_combine<<<128, blk, 0, stream>>>(Al, hloc, sc);
        scan_part2<<<dim3(64, NC, 2), blk, 0, stream>>>(dtb, xin, proj, Al, hloc,
                                                        Dp + i * 1024, xzb, ysb);
        gemm3<false, 0, true, true, false><<<dim3(8, 32), blk, 0, stream>>>(
            ysb, 1024, wt_mo + (size_t)i * 512 * 1024, 1024,
            nullptr, h, 512, av, 512, nullptr, 0, 2000, 512, 1024, 0, 0, 0);
        ln_k<false, false><<<500, blk, 0, stream>>>(av, ln2_g + i * 512, ln2_b + i * 512,
                                                    lnb, 2000);
        dcconv31_k<<<4000, blk, 0, stream>>>(lnb, av, dcwt + i * 31 * 512,
                                             dc_b + i * 512, h, hb);
    }

    gemm3<true, 0, false, true, false><<<dim3(9, 32), blk, 0, stream>>>(
        hb, 512, wt_out, 512, b_out, nullptr, 0, (float*)d_out, 514, nullptr, 0,
        2000, 514, 512, 0, 0, 0);
    mask_k<<<8, blk, 0, stream>>>(lengths, (float*)d_out + 2000 * 514);
}

// Round 8
// 753.407 us; speedup vs baseline: 1.6330x; 1.0026x over previous
//
#include <hip/hip_runtime.h>
#include <cstdint>
#include <cstddef>

#define DEVI static __device__ __forceinline__

typedef unsigned short ushort_t;
typedef __attribute__((ext_vector_type(8))) short short8;
typedef __attribute__((ext_vector_type(4))) float f32x4;

DEVI float sp_softplus(float x) { return x > 20.f ? x : log1pf(__expf(x)); }
DEVI float silu_f(float x)      { return x / (1.f + __expf(-x)); }

DEVI ushort_t f2b(float v) {
    uint32_t u = __builtin_bit_cast(uint32_t, v);
    u += 0x7FFFu + ((u >> 16) & 1u);
    return (ushort_t)(u >> 16);
}
DEVI float b2f(ushort_t u) {
    uint32_t x = ((uint32_t)u) << 16;
    return __builtin_bit_cast(float, x);
}

DEVI void gload16(const ushort_t* g, ushort_t* l) {
    __builtin_amdgcn_global_load_lds(
        (const __attribute__((address_space(1))) unsigned int*)g,
        (__attribute__((address_space(3))) unsigned int*)l, 16, 0, 0);
}

#define NC 8
#define CL 125

// ---------------- LayerNorm: one wave per row of 512 ----------------
template<bool RELU, bool OUTB16>
__global__ __launch_bounds__(256) void ln_k(const float* __restrict__ x,
                                            const float* __restrict__ g,
                                            const float* __restrict__ b,
                                            void* __restrict__ yv, int M)
{
    int wid  = threadIdx.x >> 6;
    int lane = threadIdx.x & 63;
    int row  = blockIdx.x * 4 + wid;
    if (row >= M) return;
    const float* xr = x + (size_t)row * 512;
    float4 v0 = *(const float4*)(xr + lane * 8);
    float4 v1 = *(const float4*)(xr + lane * 8 + 4);
    float vals[8] = {v0.x, v0.y, v0.z, v0.w, v1.x, v1.y, v1.z, v1.w};
    float s = 0.f;
#pragma unroll
    for (int i = 0; i < 8; i++) s += vals[i];
#pragma unroll
    for (int off = 1; off < 64; off <<= 1) s += __shfl_xor(s, off);
    float mu = s * (1.f / 512.f);
    float q = 0.f;
#pragma unroll
    for (int i = 0; i < 8; i++) { float d = vals[i] - mu; q += d * d; }
#pragma unroll
    for (int off = 1; off < 64; off <<= 1) q += __shfl_xor(q, off);
    float rstd = rsqrtf(q * (1.f / 512.f) + 1e-5f);
#pragma unroll
    for (int i = 0; i < 8; i++) {
        int c = lane * 8 + i;
        float o = (vals[i] - mu) * rstd * g[c] + b[c];
        if (RELU) o = fmaxf(o, 0.f);
        if (OUTB16) ((ushort_t*)yv)[(size_t)row * 512 + c] = f2b(o);
        else        ((float*)yv)[(size_t)row * 512 + c] = o;
    }
}

// ---------------- converters ----------------
__global__ __launch_bounds__(256) void cvt_x_k(const float* __restrict__ x,
                                               ushort_t* __restrict__ xb)
{
    int e = blockIdx.x * 256 + threadIdx.x;
    if (e >= 2000 * 288) return;
    int k = e % 288, row = e / 288;
    xb[e] = (k < 257) ? f2b(x[(size_t)row * 257 + k]) : (ushort_t)0;
}

// small weight reshapes: conv4 w -> [4][1024], dc w -> [31][512], W_xproj -> bf16
__global__ __launch_bounds__(256) void prep_small_k(const float* __restrict__ conv_w,
                                                    const float* __restrict__ dc_w,
                                                    const float* __restrict__ W_xproj,
                                                    float* __restrict__ cwt,
                                                    float* __restrict__ dcwt,
                                                    ushort_t* __restrict__ wxb)
{
    int e = blockIdx.x * 256 + threadIdx.x;
    if (e < 16384) {
        int l = e >> 12, rem = e & 4095, k = rem >> 10, d = rem & 1023;
        cwt[e] = conv_w[l * 4096 + d * 4 + k];
        return;
    }
    e -= 16384;
    if (e < 63488) {
        int l = e / 15872, rem = e % 15872, k = rem / 512, m = rem % 512;
        dcwt[e] = dc_w[l * 15872 + m * 31 + k];
        return;
    }
    e -= 63488;
    if (e < 262144) wxb[e] = f2b(W_xproj[e]);
}

// transpose+convert: src f32 [K][N] (ld srcld) -> dst bf16 [N][ldo], zero-pad k>=Ktrue
__global__ __launch_bounds__(256) void tr_w_k(const float* __restrict__ src,
                                              ushort_t* __restrict__ dst,
                                              int Ktrue, int N, int ldo, int srcld,
                                              size_t sstride, size_t dstride)
{
    __shared__ float tile[32][33];
    src += blockIdx.z * sstride;
    dst += blockIdx.z * dstride;
    int n0 = blockIdx.x * 32, k0 = blockIdx.y * 32;
    int tx = threadIdx.x & 31, ty = threadIdx.x >> 5;
#pragma unroll
    for (int r = 0; r < 4; r++) {
        int k = k0 + ty + r * 8, n = n0 + tx;
        tile[ty + r * 8][tx] = (k < Ktrue && n < N) ? src[(size_t)k * srcld + n] : 0.f;
    }
    __syncthreads();
#pragma unroll
    for (int r = 0; r < 4; r++) {
        int n = n0 + ty + r * 8;
        if (n < N) dst[(size_t)n * ldo + k0 + tx] = f2b(tile[tx][ty + r * 8]);
    }
}

// ---------------- bf16 MFMA GEMM: 64x64 tile, BK=32, 4-buffer counted-vmcnt pipeline ----
// A: bf16 [M][lda] (K contig). Bt: bf16 [N][ldb] (K contig). 4 waves in 2x2,
// each wave owns 32x32. K % 32 == 0. 3 stages in flight; vmcnt never 0 in
// steady state (T4). LDS 32KB -> 5 blocks/CU. XCD-bijective block swizzle.
// ACT: 0 none, 1 softplus(+bias), 2 split dt/proj epilogue.
template<bool BIAS, int ACT, bool RES, bool OUTF32, bool OUTB16>
__global__ __launch_bounds__(256) void gemm4(
    const ushort_t* __restrict__ A, int lda,
    const ushort_t* __restrict__ Bt, int ldb,
    const float* __restrict__ bias,
    const float* __restrict__ R, int ldr,
    float* __restrict__ C, int ldc,
    ushort_t* __restrict__ C2, int ldc2,
    int M, int N, int K,
    size_t aStr, size_t bStr, size_t cStr)
{
    __shared__ ushort_t As[4][4 * 64 * 8];
    __shared__ ushort_t Bs[4][4 * 64 * 8];
    A  += blockIdx.z * aStr;
    Bt += blockIdx.z * bStr;
    C  += blockIdx.z * cStr;
    C2 += blockIdx.z * cStr;

    int tid = threadIdx.x;
    int wid = tid >> 6, l = tid & 63;
    int wr = wid >> 1, wc = wid & 1;
    int lk = l >> 4, lr = l & 15;

    // bijective XCD swizzle (m204 general form)
    int nwg = gridDim.x * gridDim.y;
    int bid = blockIdx.y * gridDim.x + blockIdx.x;
    {
        int q = nwg >> 3, r = nwg & 7;
        int xcd = bid & 7, lo = bid >> 3;
        bid = (xcd < r ? xcd * (q + 1) : r * (q + 1) + (xcd - r) * q) + lo;
    }
    int bx = bid % gridDim.x, by = bid / gridDim.x;
    int bm = by * 64, bn = bx * 64;

    f32x4 acc[2][2];
#pragma unroll
    for (int m = 0; m < 2; m++)
#pragma unroll
        for (int n = 0; n < 2; n++) acc[m][n] = (f32x4){0.f, 0.f, 0.f, 0.f};

    // stage one BK=32 tile: kb = wid (k-subtile of 8), row = l
    auto stage = [&](int buf, int k0) {
        gload16(A  + (size_t)(bm + l) * lda + k0 + wid * 8, &As[buf][(wid * 64 + l) * 8]);
        gload16(Bt + (size_t)(bn + l) * ldb + k0 + wid * 8, &Bs[buf][(wid * 64 + l) * 8]);
    };

    auto compute = [&](int buf) {
        short8 af[2], bf[2];
#pragma unroll
        for (int m = 0; m < 2; m++) {
            int row = wr * 32 + m * 16 + lr;
            af[m] = *(const short8*)&As[buf][(lk * 64 + row) * 8];
        }
#pragma unroll
        for (int n = 0; n < 2; n++) {
            int col = wc * 32 + n * 16 + lr;
            bf[n] = *(const short8*)&Bs[buf][(lk * 64 + col) * 8];
        }
#pragma unroll
        for (int m = 0; m < 2; m++)
#pragma unroll
            for (int n = 0; n < 2; n++)
                acc[m][n] = __builtin_amdgcn_mfma_f32_16x16x32_bf16(
                    af[m], bf[n], acc[m][n], 0, 0, 0);
    };

    int nt = K >> 5;
    for (int t = 0; t < 3 && t < nt; t++) stage(t, t * 32);
    for (int t = 0; t < nt; t++) {
        int rem = nt - t;                 // stages outstanding at loop top (<=3)
        if (rem >= 3)      asm volatile("s_waitcnt vmcnt(4)" ::: "memory");
        else if (rem == 2) asm volatile("s_waitcnt vmcnt(2)" ::: "memory");
        else               asm volatile("s_waitcnt vmcnt(0)" ::: "memory");
        __syncthreads();
        if (t + 3 < nt) stage((t + 3) & 3, (t + 3) * 32);
        compute(t & 3);
    }

    // epilogue: C/D layout col = lane&15, row = (lane>>4)*4 + r
#pragma unroll
    for (int m = 0; m < 2; m++) {
#pragma unroll
        for (int n = 0; n < 2; n++) {
            int gn = bn + wc * 32 + n * 16 + lr;
            if (gn >= N) continue;
#pragma unroll
            for (int r = 0; r < 4; r++) {
                int gm = bm + wr * 32 + m * 16 + lk * 4 + r;
                if (gm >= M) continue;
                float v = acc[m][n][r];
                if (ACT == 2) {
                    if (gn < 1024) C[(size_t)gm * ldc + gn] = sp_softplus(v + bias[gn]);
                    else ((float*)R)[(size_t)gm * ldr + (gn - 1024) + 32] = v;
                    continue;
                }
                if (BIAS) v += bias[gn];
                if (ACT == 1) v = sp_softplus(v);
                if (RES) v += R[(size_t)gm * ldr + gn];
                if (OUTF32) C[(size_t)gm * ldc + gn] = v;
                if (OUTB16) C2[(size_t)gm * ldc2 + gn] = f2b(v);
            }
        }
    }
}

// ---------------- causal depthwise conv (K=4) + SiLU ----------------
__global__ __launch_bounds__(256) void conv4_silu_k(const ushort_t* __restrict__ xzb,
                                                    const float* __restrict__ cwt,
                                                    const float* __restrict__ bias,
                                                    float* __restrict__ xin,
                                                    ushort_t* __restrict__ xinb)
{
    int e = blockIdx.x * 256 + threadIdx.x;
    if (e >= 2000 * 1024) return;
    int d = e & 1023;
    int row = e >> 10;
    int b = row >= 1000 ? 1 : 0;
    int t = row - b * 1000;
    float acc = bias[d];
#pragma unroll
    for (int k = 0; k < 4; k++) {
        int tt = t - 3 + k;
        if (tt >= 0) acc += b2f(xzb[((size_t)(b * 1000 + tt)) * 2048 + d]) * cwt[k * 1024 + d];
    }
    float v = silu_f(acc);
    xin[(size_t)row * 1024 + d] = v;
    xinb[(size_t)row * 1024 + d] = f2b(v);
}

// ---------------- chunked selective scan ----------------
__global__ __launch_bounds__(256) void scan_part1(const float* __restrict__ dt,
                                                  const float* __restrict__ xin,
                                                  const float* __restrict__ proj,
                                                  const float* __restrict__ A_log,
                                                  float* __restrict__ hloc,
                                                  float* __restrict__ sc)
{
    __shared__ float s_dt[CL][16], s_x[CL][16], s_B[CL][16];
    int d0 = blockIdx.x * 16;
    int c  = blockIdx.y;
    int b  = blockIdx.z;
    int tid = threadIdx.x;
    int ch = tid >> 4, st = tid & 15;
    int d = d0 + ch;
    float a_s = -__expf(A_log[d * 16 + st]);
    int base = b * 1000 + c * CL;
    for (int lin = tid; lin < CL * 16; lin += 256) {
        int tt = lin >> 4, j = lin & 15;
        size_t row = (size_t)(base + tt);
        s_dt[tt][j] = dt[row * 1024 + d0 + j];
        s_x[tt][j]  = xin[row * 1024 + d0 + j];
        s_B[tt][j]  = proj[row * 64 + 32 + j];
    }
    __syncthreads();
    float h = 0.f, sdt = 0.f;
    for (int t0 = 0; t0 < CL; t0 += 5) {
        float dA[5], du[5];
#pragma unroll
        for (int u = 0; u < 5; u++) {
            float dtv = s_dt[t0 + u][ch];
            dA[u] = __expf(dtv * a_s);
            du[u] = dtv * s_x[t0 + u][ch] * s_B[t0 + u][st];
            sdt += dtv;
        }
#pragma unroll
        for (int u = 0; u < 5; u++) h = dA[u] * h + du[u];
    }
    hloc[((size_t)(b * NC + c) << 14) + ((size_t)d << 4) + st] = h;
    if (st == 0) sc[(b * NC + c) * 1024 + d] = sdt;
}

__global__ __launch_bounds__(256) void scan_combine(const float* __restrict__ A_log,
                                                    float* __restrict__ hloc,
                                                    const float* __restrict__ sc)
{
    int e = blockIdx.x * 256 + threadIdx.x;
    if (e >= 2 * 16384) return;
    int b = e >> 14;
    int rem = e & 16383;
    int dd = rem >> 4;
    float a_s = -__expf(A_log[rem]);
    float H = hloc[((size_t)(b * NC) << 14) + rem];
    for (int c = 1; c < NC; c++) {
        size_t idx = ((size_t)(b * NC + c) << 14) + rem;
        H = hloc[idx] + __expf(a_s * sc[(b * NC + c) * 1024 + dd]) * H;
        hloc[idx] = H;
    }
}

// part2 + fused gating: writes ysb = bf16((y + xin*Dp) * silu(z))
__global__ __launch_bounds__(256) void scan_part2(const float* __restrict__ dt,
                                                  const float* __restrict__ xin,
                                                  const float* __restrict__ proj,
                                                  const float* __restrict__ A_log,
                                                  const float* __restrict__ hend,
                                                  const float* __restrict__ Dp,
                                                  const ushort_t* __restrict__ xzb,
                                                  ushort_t* __restrict__ ysb)
{
    __shared__ float s_dt[CL][16], s_x[CL][16], s_B[CL][16], s_C[CL][16], s_y[CL][16];
    int d0 = blockIdx.x * 16;
    int c  = blockIdx.y;
    int b  = blockIdx.z;
    int tid = threadIdx.x;
    int ch = tid >> 4, st = tid & 15;
    int d = d0 + ch;
    float a_s = -__expf(A_log[d * 16 + st]);
    int base = b * 1000 + c * CL;
    for (int lin = tid; lin < CL * 16; lin += 256) {
        int tt = lin >> 4, j = lin & 15;
        size_t row = (size_t)(base + tt);
        s_dt[tt][j] = dt[row * 1024 + d0 + j];
        s_x[tt][j]  = xin[row * 1024 + d0 + j];
        s_B[tt][j]  = proj[row * 64 + 32 + j];
        s_C[tt][j]  = proj[row * 64 + 48 + j];
    }
    float h = 0.f;
    if (c > 0) h = hend[((size_t)(b * NC + c - 1) << 14) + ((size_t)d << 4) + st];
    __syncthreads();
    for (int t0 = 0; t0 < CL; t0 += 5) {
        float dA[5], du[5], p[5];
#pragma unroll
        for (int u = 0; u < 5; u++) {
            float dtv = s_dt[t0 + u][ch];
            dA[u] = __expf(dtv * a_s);
            du[u] = dtv * s_x[t0 + u][ch] * s_B[t0 + u][st];
        }
#pragma unroll
        for (int u = 0; u < 5; u++) {
            h = dA[u] * h + du[u];
            p[u] = h * s_C[t0 + u][st];
        }
#pragma unroll
        for (int u = 0; u < 5; u++) {
            p[u] += __shfl_xor(p[u], 1);
            p[u] += __shfl_xor(p[u], 2);
            p[u] += __shfl_xor(p[u], 4);
            p[u] += __shfl_xor(p[u], 8);
            if (st == 0) s_y[t0 + u][ch] = p[u];
        }
    }
    __syncthreads();
    for (int lin = tid; lin < CL * 16; lin += 256) {
        int tt = lin >> 4, j = lin & 15;
        size_t row = (size_t)(base + tt);
        float z = b2f(xzb[row * 2048 + 1024 + d0 + j]);
        float yv = (s_y[tt][j] + s_x[tt][j] * Dp[d0 + j]) * silu_f(z);
        ysb[row * 1024 + d0 + j] = f2b(yv);
    }
}

// ---------------- depthwise conv31 + residual (coalesced weights) ----------------
__global__ __launch_bounds__(256) void dcconv31_k(const float* __restrict__ ln,
                                                  const float* __restrict__ a,
                                                  const float* __restrict__ dcwt,
                                                  const float* __restrict__ bias,
                                                  float* __restrict__ h,
                                                  ushort_t* __restrict__ hb)
{
    int e = blockIdx.x * 256 + threadIdx.x;
    if (e >= 2000 * 512) return;
    int m = e & 511;
    int row = e >> 9;
    int b = row >= 1000 ? 1 : 0;
    int t = row - b * 1000;
    float acc = bias[m];
#pragma unroll
    for (int k = 0; k < 31; k++) {
        int tt = t - 15 + k;
        if (tt >= 0 && tt < 1000)
            acc += ln[((size_t)(b * 1000 + tt)) * 512 + m] * dcwt[k * 512 + m];
    }
    float v = a[e] + acc;
    h[e] = v;
    hb[e] = f2b(v);
}

// ---------------- seq_mask output ----------------
__global__ void mask_k(const int* __restrict__ lengths, float* __restrict__ out)
{
    int i = blockIdx.x * 256 + threadIdx.x;
    if (i >= 2000) return;
    out[i] = ((i % 1000) < lengths[i / 1000]) ? 1.f : 0.f;
}

extern "C" void kernel_launch(void* const* d_in, const int* in_sizes, int n_in,
                              void* d_out, int out_size, void* d_ws, size_t ws_size,
                              hipStream_t stream)
{
    const float* x       = (const float*)d_in[0];
    const int*   lengths = (const int*)  d_in[1];
    const float* w_in0   = (const float*)d_in[2];
    const float* ln_in_g = (const float*)d_in[3];
    const float* ln_in_b = (const float*)d_in[4];
    const float* ln1_g   = (const float*)d_in[5];
    const float* ln1_b   = (const float*)d_in[6];
    const float* W_inproj= (const float*)d_in[7];
    const float* conv_w  = (const float*)d_in[8];
    const float* conv_b  = (const float*)d_in[9];
    const float* W_xproj = (const float*)d_in[10];
    const float* W_dt    = (const float*)d_in[11];
    const float* b_dt    = (const float*)d_in[12];
    const float* A_log   = (const float*)d_in[13];
    const float* Dp      = (const float*)d_in[14];
    const float* W_mo    = (const float*)d_in[15];
    const float* ln2_g   = (const float*)d_in[16];
    const float* ln2_b   = (const float*)d_in[17];
    const float* dc_w    = (const float*)d_in[18];
    const float* dc_b    = (const float*)d_in[19];
    const float* w_out   = (const float*)d_in[20];
    const float* b_out   = (const float*)d_in[21];

    char* p = (char*)d_ws;
    auto alloc_f = [&](size_t n) { float* r = (float*)p; p += n * 4; return r; };
    auto alloc_b = [&](size_t n) { ushort_t* r = (ushort_t*)p; p += n * 2; return r; };

    float* h    = alloc_f(2048 * 512);
    float* lnb  = alloc_f(2048 * 512);
    float* xin  = alloc_f(2048 * 1024);
    float* proj = alloc_f(2048 * 64);
    float* dtb  = alloc_f(2048 * 1024);
    float* av   = alloc_f(2048 * 512);
    float* hloc = alloc_f(262144);
    float* sc   = alloc_f(16384);
    float* cwt  = alloc_f(4 * 4 * 1024);
    float* dcwt = alloc_f(4 * 31 * 512);
    ushort_t* xbf   = alloc_b(2048 * 288);
    ushort_t* lnbb  = alloc_b(2048 * 512);
    ushort_t* xzb   = alloc_b(2048 * 2048);
    ushort_t* xinb  = alloc_b(2048 * 1024);
    ushort_t* ysb   = alloc_b(2048 * 1024);
    ushort_t* hb    = alloc_b(2048 * 512);
    ushort_t* wt_in0 = alloc_b(512 * 288);
    ushort_t* wt_in  = alloc_b((size_t)4 * 2048 * 512);
    ushort_t* wt_dt  = alloc_b((size_t)4 * 1024 * 32);
    ushort_t* wt_mo  = alloc_b((size_t)4 * 512 * 1024);
    ushort_t* wt_out = alloc_b(576 * 512);
    ushort_t* wxb    = alloc_b((size_t)4 * 1024 * 64);
    ushort_t* wt_big = alloc_b((size_t)4 * 1152 * 1024);

    dim3 blk(256);

    // ---- weight prep ----
    cvt_x_k<<<(2000 * 288 + 255) / 256, blk, 0, stream>>>(x, xbf);
    prep_small_k<<<(16384 + 63488 + 262144 + 255) / 256, blk, 0, stream>>>(
        conv_w, dc_w, W_xproj, cwt, dcwt, wxb);
    tr_w_k<<<dim3(16, 9, 1),  blk, 0, stream>>>(w_in0, wt_in0, 257, 512, 288, 512, 0, 0);
    tr_w_k<<<dim3(64, 16, 4), blk, 0, stream>>>(W_inproj, wt_in, 512, 2048, 512, 2048,
                                                (size_t)512 * 2048, (size_t)2048 * 512);
    tr_w_k<<<dim3(32, 1, 4),  blk, 0, stream>>>(W_dt, wt_dt, 32, 1024, 32, 1024,
                                                (size_t)32 * 1024, (size_t)1024 * 32);
    tr_w_k<<<dim3(16, 32, 4), blk, 0, stream>>>(W_mo, wt_mo, 1024, 512, 1024, 512,
                                                (size_t)1024 * 512, (size_t)512 * 1024);
    tr_w_k<<<dim3(17, 16, 1), blk, 0, stream>>>(w_out, wt_out, 512, 514, 512, 514, 0, 0);
    // W_x[:,32:64] transposed into wt_big rows 1024..1055
    tr_w_k<<<dim3(1, 32, 4),  blk, 0, stream>>>(W_xproj + 32, wt_big + (size_t)1024 * 1024,
                                                1024, 32, 1024, 64,
                                                (size_t)1024 * 64, (size_t)1152 * 1024);
    // W_comb (batched over 4 layers): wt_big[j][k] = sum_r W_dt[r][j] * W_x[k][r]
    gemm4<false, 0, false, false, true><<<dim3(16, 16, 4), blk, 0, stream>>>(
        wt_dt, 32, wxb, 64, nullptr, nullptr, 0, nullptr, 0, wt_big, 1024,
        1024, 1024, 32,
        (size_t)1024 * 32, (size_t)1024 * 64, (size_t)1152 * 1024);

    // ---- input projection + LN/relu ----
    gemm4<false, 0, false, true, false><<<dim3(8, 32), blk, 0, stream>>>(
        xbf, 288, wt_in0, 288, nullptr, nullptr, 0, lnb, 512, nullptr, 0,
        2000, 512, 288, 0, 0, 0);
    ln_k<true, false><<<500, blk, 0, stream>>>(lnb, ln_in_g, ln_in_b, h, 2000);

    for (int i = 0; i < 4; i++) {
        const float* Al = A_log + (size_t)i * 16384;
        ln_k<false, true><<<500, blk, 0, stream>>>(h, ln1_g + i * 512, ln1_b + i * 512,
                                                   lnbb, 2000);
        gemm4<false, 0, false, false, true><<<dim3(32, 32), blk, 0, stream>>>(
            lnbb, 512, wt_in + (size_t)i * 2048 * 512, 512,
            nullptr, nullptr, 0, nullptr, 0, xzb, 2048, 2000, 2048, 512, 0, 0, 0);
        conv4_silu_k<<<8000, blk, 0, stream>>>(xzb, cwt + i * 4096,
                                               conv_b + i * 1024, xin, xinb);
        // fused xproj+dt: N=1056 (1024 dt | 32 B,C)
        gemm4<false, 2, false, false, false><<<dim3(17, 32), blk, 0, stream>>>(
            xinb, 1024, wt_big + (size_t)i * 1152 * 1024, 1024,
            b_dt + i * 1024, proj, 64, dtb, 1024, nullptr, 0, 2000, 1056, 1024, 0, 0, 0);
        scan_part1<<<dim3(64, NC, 2), blk, 0, stream>>>(dtb, xin, proj, Al, hloc, sc);
        scan_combine<<<128, blk, 0, stream>>>(Al, hloc, sc);
        scan_part2<<<dim3(64, NC, 2), blk, 0, stream>>>(dtb, xin, proj, Al, hloc,
                                                        Dp + i * 1024, xzb, ysb);
        gemm4<false, 0, true, true, false><<<dim3(8, 32), blk, 0, stream>>>(
            ysb, 1024, wt_mo + (size_t)i * 512 * 1024, 1024,
            nullptr, h, 512, av, 512, nullptr, 0, 2000, 512, 1024, 0, 0, 0);
        ln_k<false, false><<<500, blk, 0, stream>>>(av, ln2_g + i * 512, ln2_b + i * 512,
                                                    lnb, 2000);
        dcconv31_k<<<4000, blk, 0, stream>>>(lnb, av, dcwt + i * 31 * 512,
                                             dc_b + i * 512, h, hb);
    }

    gemm4<true, 0, false, true, false><<<dim3(9, 32), blk, 0, stream>>>(
        hb, 512, wt_out, 512, b_out, nullptr, 0, (float*)d_out, 514, nullptr, 0,
        2000, 514, 512, 0, 0, 0);
    mask_k<<<8, blk, 0, stream>>>(lengths, (float*)d_out + 2000 * 514);
}

// Round 9
// 736.771 us; speedup vs baseline: 1.6699x; 1.0226x over previous
//
#include <hip/hip_runtime.h>
#include <cstdint>
#include <cstddef>

#define DEVI static __device__ __forceinline__

typedef unsigned short ushort_t;
typedef __attribute__((ext_vector_type(8))) short short8;
typedef __attribute__((ext_vector_type(4))) float f32x4;

DEVI float sp_softplus(float x) { return x > 20.f ? x : log1pf(__expf(x)); }
DEVI float silu_f(float x)      { return x / (1.f + __expf(-x)); }

DEVI ushort_t f2b(float v) {
    uint32_t u = __builtin_bit_cast(uint32_t, v);
    u += 0x7FFFu + ((u >> 16) & 1u);
    return (ushort_t)(u >> 16);
}
DEVI float b2f(ushort_t u) {
    uint32_t x = ((uint32_t)u) << 16;
    return __builtin_bit_cast(float, x);
}

DEVI void gload16(const ushort_t* g, ushort_t* l) {
    __builtin_amdgcn_global_load_lds(
        (const __attribute__((address_space(1))) unsigned int*)g,
        (__attribute__((address_space(3))) unsigned int*)l, 16, 0, 0);
}

#define NC 8
#define CL 125

// ---------------- LayerNorm: one wave per row of 512 ----------------
template<bool RELU, bool OUTB16>
__global__ __launch_bounds__(256) void ln_k(const float* __restrict__ x,
                                            const float* __restrict__ g,
                                            const float* __restrict__ b,
                                            void* __restrict__ yv, int M)
{
    int wid  = threadIdx.x >> 6;
    int lane = threadIdx.x & 63;
    int row  = blockIdx.x * 4 + wid;
    if (row >= M) return;
    const float* xr = x + (size_t)row * 512;
    float4 v0 = *(const float4*)(xr + lane * 8);
    float4 v1 = *(const float4*)(xr + lane * 8 + 4);
    float vals[8] = {v0.x, v0.y, v0.z, v0.w, v1.x, v1.y, v1.z, v1.w};
    float s = 0.f;
#pragma unroll
    for (int i = 0; i < 8; i++) s += vals[i];
#pragma unroll
    for (int off = 1; off < 64; off <<= 1) s += __shfl_xor(s, off);
    float mu = s * (1.f / 512.f);
    float q = 0.f;
#pragma unroll
    for (int i = 0; i < 8; i++) { float d = vals[i] - mu; q += d * d; }
#pragma unroll
    for (int off = 1; off < 64; off <<= 1) q += __shfl_xor(q, off);
    float rstd = rsqrtf(q * (1.f / 512.f) + 1e-5f);
#pragma unroll
    for (int i = 0; i < 8; i++) {
        int c = lane * 8 + i;
        float o = (vals[i] - mu) * rstd * g[c] + b[c];
        if (RELU) o = fmaxf(o, 0.f);
        if (OUTB16) ((ushort_t*)yv)[(size_t)row * 512 + c] = f2b(o);
        else        ((float*)yv)[(size_t)row * 512 + c] = o;
    }
}

// ---------------- converters ----------------
__global__ __launch_bounds__(256) void cvt_x_k(const float* __restrict__ x,
                                               ushort_t* __restrict__ xb)
{
    int e = blockIdx.x * 256 + threadIdx.x;
    if (e >= 2000 * 288) return;
    int k = e % 288, row = e / 288;
    xb[e] = (k < 257) ? f2b(x[(size_t)row * 257 + k]) : (ushort_t)0;
}

// small weight reshapes: conv4 w -> [4][1024], dc w -> [31][512], W_xproj -> bf16
__global__ __launch_bounds__(256) void prep_small_k(const float* __restrict__ conv_w,
                                                    const float* __restrict__ dc_w,
                                                    const float* __restrict__ W_xproj,
                                                    float* __restrict__ cwt,
                                                    float* __restrict__ dcwt,
                                                    ushort_t* __restrict__ wxb)
{
    int e = blockIdx.x * 256 + threadIdx.x;
    if (e < 16384) {
        int l = e >> 12, rem = e & 4095, k = rem >> 10, d = rem & 1023;
        cwt[e] = conv_w[l * 4096 + d * 4 + k];
        return;
    }
    e -= 16384;
    if (e < 63488) {
        int l = e / 15872, rem = e % 15872, k = rem / 512, m = rem % 512;
        dcwt[e] = dc_w[l * 15872 + m * 31 + k];
        return;
    }
    e -= 63488;
    if (e < 262144) wxb[e] = f2b(W_xproj[e]);
}

// transpose+convert: src f32 [K][N] (ld srcld) -> dst bf16 [N][ldo], zero-pad k>=Ktrue
__global__ __launch_bounds__(256) void tr_w_k(const float* __restrict__ src,
                                              ushort_t* __restrict__ dst,
                                              int Ktrue, int N, int ldo, int srcld,
                                              size_t sstride, size_t dstride)
{
    __shared__ float tile[32][33];
    src += blockIdx.z * sstride;
    dst += blockIdx.z * dstride;
    int n0 = blockIdx.x * 32, k0 = blockIdx.y * 32;
    int tx = threadIdx.x & 31, ty = threadIdx.x >> 5;
#pragma unroll
    for (int r = 0; r < 4; r++) {
        int k = k0 + ty + r * 8, n = n0 + tx;
        tile[ty + r * 8][tx] = (k < Ktrue && n < N) ? src[(size_t)k * srcld + n] : 0.f;
    }
    __syncthreads();
#pragma unroll
    for (int r = 0; r < 4; r++) {
        int n = n0 + ty + r * 8;
        if (n < N) dst[(size_t)n * ldo + k0 + tx] = f2b(tile[tx][ty + r * 8]);
    }
}

// ---- bf16 MFMA GEMM: 64x64 tile, BK=32, 4-buffer counted-vmcnt + RAW barrier ----
// Per-wave counted vmcnt (never 0 in steady state) + __builtin_amdgcn_s_barrier
// (NOT __syncthreads — hipcc drains vmcnt(0) before its s_barrier, defeating T4).
// Each wave stages one k-subtile; vmcnt(4) proves that wave's oldest stage done;
// barrier then proves ALL waves' stage(t) done -> buf t fully readable.
// ACT: 0 none, 1 softplus(+bias), 2 split dt(bf16,C2)/proj(f32,R) epilogue.
template<bool BIAS, int ACT, bool RES, bool OUTF32, bool OUTB16>
__global__ __launch_bounds__(256) void gemm5(
    const ushort_t* __restrict__ A, int lda,
    const ushort_t* __restrict__ Bt, int ldb,
    const float* __restrict__ bias,
    const float* __restrict__ R, int ldr,
    float* __restrict__ C, int ldc,
    ushort_t* __restrict__ C2, int ldc2,
    int M, int N, int K,
    size_t aStr, size_t bStr, size_t cStr)
{
    __shared__ ushort_t As[4][4 * 64 * 8];
    __shared__ ushort_t Bs[4][4 * 64 * 8];
    A  += blockIdx.z * aStr;
    Bt += blockIdx.z * bStr;
    C  += blockIdx.z * cStr;
    C2 += blockIdx.z * cStr;

    int tid = threadIdx.x;
    int wid = tid >> 6, l = tid & 63;
    int wr = wid >> 1, wc = wid & 1;
    int lk = l >> 4, lr = l & 15;

    // bijective XCD swizzle (m204 general form)
    int nwg = gridDim.x * gridDim.y;
    int bid = blockIdx.y * gridDim.x + blockIdx.x;
    {
        int q = nwg >> 3, r = nwg & 7;
        int xcd = bid & 7, lo = bid >> 3;
        bid = (xcd < r ? xcd * (q + 1) : r * (q + 1) + (xcd - r) * q) + lo;
    }
    int bx = bid % gridDim.x, by = bid / gridDim.x;
    int bm = by * 64, bn = bx * 64;

    f32x4 acc[2][2];
#pragma unroll
    for (int m = 0; m < 2; m++)
#pragma unroll
        for (int n = 0; n < 2; n++) acc[m][n] = (f32x4){0.f, 0.f, 0.f, 0.f};

    auto stage = [&](int buf, int k0) {
        gload16(A  + (size_t)(bm + l) * lda + k0 + wid * 8, &As[buf][(wid * 64 + l) * 8]);
        gload16(Bt + (size_t)(bn + l) * ldb + k0 + wid * 8, &Bs[buf][(wid * 64 + l) * 8]);
    };

    auto compute = [&](int buf) {
        short8 af[2], bf[2];
#pragma unroll
        for (int m = 0; m < 2; m++) {
            int row = wr * 32 + m * 16 + lr;
            af[m] = *(const short8*)&As[buf][(lk * 64 + row) * 8];
        }
#pragma unroll
        for (int n = 0; n < 2; n++) {
            int col = wc * 32 + n * 16 + lr;
            bf[n] = *(const short8*)&Bs[buf][(lk * 64 + col) * 8];
        }
#pragma unroll
        for (int m = 0; m < 2; m++)
#pragma unroll
            for (int n = 0; n < 2; n++)
                acc[m][n] = __builtin_amdgcn_mfma_f32_16x16x32_bf16(
                    af[m], bf[n], acc[m][n], 0, 0, 0);
    };

    int nt = K >> 5;
    for (int t = 0; t < 3 && t < nt; t++) stage(t, t * 32);
    for (int t = 0; t < nt; t++) {
        int rem = nt - t;                 // stages outstanding at loop top (<=3)
        if (rem >= 3)      asm volatile("s_waitcnt vmcnt(4)" ::: "memory");
        else if (rem == 2) asm volatile("s_waitcnt vmcnt(2)" ::: "memory");
        else               asm volatile("s_waitcnt vmcnt(0)" ::: "memory");
        __builtin_amdgcn_s_barrier();     // raw: no compiler-forced vmcnt(0) drain
        if (t + 3 < nt) stage((t + 3) & 3, (t + 3) * 32);
        compute(t & 3);
    }

    // epilogue: C/D layout col = lane&15, row = (lane>>4)*4 + r
#pragma unroll
    for (int m = 0; m < 2; m++) {
#pragma unroll
        for (int n = 0; n < 2; n++) {
            int gn = bn + wc * 32 + n * 16 + lr;
            if (gn >= N) continue;
#pragma unroll
            for (int r = 0; r < 4; r++) {
                int gm = bm + wr * 32 + m * 16 + lk * 4 + r;
                if (gm >= M) continue;
                float v = acc[m][n][r];
                if (ACT == 2) {
                    if (gn < 1024) C2[(size_t)gm * ldc2 + gn] = f2b(sp_softplus(v + bias[gn]));
                    else ((float*)R)[(size_t)gm * ldr + (gn - 1024) + 32] = v;
                    continue;
                }
                if (BIAS) v += bias[gn];
                if (ACT == 1) v = sp_softplus(v);
                if (RES) v += R[(size_t)gm * ldr + gn];
                if (OUTF32) C[(size_t)gm * ldc + gn] = v;
                if (OUTB16) C2[(size_t)gm * ldc2 + gn] = f2b(v);
            }
        }
    }
}

// ---------------- causal depthwise conv (K=4) + SiLU, vectorized x8 ----------------
__global__ __launch_bounds__(256) void conv4_silu_k(const ushort_t* __restrict__ xzb,
                                                    const float* __restrict__ cwt,
                                                    const float* __restrict__ bias,
                                                    ushort_t* __restrict__ xinb)
{
    int e = blockIdx.x * 256 + threadIdx.x;   // 2000*128
    if (e >= 2000 * 128) return;
    int dg = (e & 127) * 8;
    int row = e >> 7;
    int b = row >= 1000 ? 1 : 0;
    int t = row - b * 1000;
    float acc[8];
#pragma unroll
    for (int j = 0; j < 8; j++) acc[j] = bias[dg + j];
#pragma unroll
    for (int k = 0; k < 4; k++) {
        int tt = t - 3 + k;
        if (tt < 0) continue;
        short8 v = *(const short8*)&xzb[(size_t)(b * 1000 + tt) * 2048 + dg];
#pragma unroll
        for (int j = 0; j < 8; j++)
            acc[j] += b2f((ushort_t)v[j]) * cwt[k * 1024 + dg + j];
    }
    short8 o;
#pragma unroll
    for (int j = 0; j < 8; j++) o[j] = (short)f2b(silu_f(acc[j]));
    *(short8*)&xinb[(size_t)row * 1024 + dg] = o;
}

// ---------------- chunked selective scan (bf16 dt/xin inputs) ----------------
__global__ __launch_bounds__(256) void scan_part1(const ushort_t* __restrict__ dt,
                                                  const ushort_t* __restrict__ xin,
                                                  const float* __restrict__ proj,
                                                  const float* __restrict__ A_log,
                                                  float* __restrict__ hloc,
                                                  float* __restrict__ sc)
{
    __shared__ float s_dt[CL][16], s_x[CL][16], s_B[CL][16];
    int d0 = blockIdx.x * 16;
    int c  = blockIdx.y;
    int b  = blockIdx.z;
    int tid = threadIdx.x;
    int ch = tid >> 4, st = tid & 15;
    int d = d0 + ch;
    float a_s = -__expf(A_log[d * 16 + st]);
    int base = b * 1000 + c * CL;
    for (int lin = tid; lin < CL * 16; lin += 256) {
        int tt = lin >> 4, j = lin & 15;
        size_t row = (size_t)(base + tt);
        s_dt[tt][j] = b2f(dt[row * 1024 + d0 + j]);
        s_x[tt][j]  = b2f(xin[row * 1024 + d0 + j]);
        s_B[tt][j]  = proj[row * 64 + 32 + j];
    }
    __syncthreads();
    float h = 0.f, sdt = 0.f;
    for (int t0 = 0; t0 < CL; t0 += 5) {
        float dA[5], du[5];
#pragma unroll
        for (int u = 0; u < 5; u++) {
            float dtv = s_dt[t0 + u][ch];
            dA[u] = __expf(dtv * a_s);
            du[u] = dtv * s_x[t0 + u][ch] * s_B[t0 + u][st];
            sdt += dtv;
        }
#pragma unroll
        for (int u = 0; u < 5; u++) h = dA[u] * h + du[u];
    }
    hloc[((size_t)(b * NC + c) << 14) + ((size_t)d << 4) + st] = h;
    if (st == 0) sc[(b * NC + c) * 1024 + d] = sdt;
}

__global__ __launch_bounds__(256) void scan_combine(const float* __restrict__ A_log,
                                                    float* __restrict__ hloc,
                                                    const float* __restrict__ sc)
{
    int e = blockIdx.x * 256 + threadIdx.x;
    if (e >= 2 * 16384) return;
    int b = e >> 14;
    int rem = e & 16383;
    int dd = rem >> 4;
    float a_s = -__expf(A_log[rem]);
    float H = hloc[((size_t)(b * NC) << 14) + rem];
    for (int c = 1; c < NC; c++) {
        size_t idx = ((size_t)(b * NC + c) << 14) + rem;
        H = hloc[idx] + __expf(a_s * sc[(b * NC + c) * 1024 + dd]) * H;
        hloc[idx] = H;
    }
}

// part2 + fused gating: writes ysb = bf16((y + xin*Dp) * silu(z))
__global__ __launch_bounds__(256) void scan_part2(const ushort_t* __restrict__ dt,
                                                  const ushort_t* __restrict__ xin,
                                                  const float* __restrict__ proj,
                                                  const float* __restrict__ A_log,
                                                  const float* __restrict__ hend,
                                                  const float* __restrict__ Dp,
                                                  const ushort_t* __restrict__ xzb,
                                                  ushort_t* __restrict__ ysb)
{
    __shared__ float s_dt[CL][16], s_x[CL][16], s_B[CL][16], s_C[CL][16], s_y[CL][16];
    int d0 = blockIdx.x * 16;
    int c  = blockIdx.y;
    int b  = blockIdx.z;
    int tid = threadIdx.x;
    int ch = tid >> 4, st = tid & 15;
    int d = d0 + ch;
    float a_s = -__expf(A_log[d * 16 + st]);
    int base = b * 1000 + c * CL;
    for (int lin = tid; lin < CL * 16; lin += 256) {
        int tt = lin >> 4, j = lin & 15;
        size_t row = (size_t)(base + tt);
        s_dt[tt][j] = b2f(dt[row * 1024 + d0 + j]);
        s_x[tt][j]  = b2f(xin[row * 1024 + d0 + j]);
        s_B[tt][j]  = proj[row * 64 + 32 + j];
        s_C[tt][j]  = proj[row * 64 + 48 + j];
    }
    float h = 0.f;
    if (c > 0) h = hend[((size_t)(b * NC + c - 1) << 14) + ((size_t)d << 4) + st];
    __syncthreads();
    for (int t0 = 0; t0 < CL; t0 += 5) {
        float dA[5], du[5], p[5];
#pragma unroll
        for (int u = 0; u < 5; u++) {
            float dtv = s_dt[t0 + u][ch];
            dA[u] = __expf(dtv * a_s);
            du[u] = dtv * s_x[t0 + u][ch] * s_B[t0 + u][st];
        }
#pragma unroll
        for (int u = 0; u < 5; u++) {
            h = dA[u] * h + du[u];
            p[u] = h * s_C[t0 + u][st];
        }
#pragma unroll
        for (int u = 0; u < 5; u++) {
            p[u] += __shfl_xor(p[u], 1);
            p[u] += __shfl_xor(p[u], 2);
            p[u] += __shfl_xor(p[u], 4);
            p[u] += __shfl_xor(p[u], 8);
            if (st == 0) s_y[t0 + u][ch] = p[u];
        }
    }
    __syncthreads();
    for (int lin = tid; lin < CL * 16; lin += 256) {
        int tt = lin >> 4, j = lin & 15;
        size_t row = (size_t)(base + tt);
        float z = b2f(xzb[row * 2048 + 1024 + d0 + j]);
        float yv = (s_y[tt][j] + s_x[tt][j] * Dp[d0 + j]) * silu_f(z);
        ysb[row * 1024 + d0 + j] = f2b(yv);
    }
}

// ---------------- depthwise conv31 + residual (coalesced weights) ----------------
__global__ __launch_bounds__(256) void dcconv31_k(const float* __restrict__ ln,
                                                  const float* __restrict__ a,
                                                  const float* __restrict__ dcwt,
                                                  const float* __restrict__ bias,
                                                  float* __restrict__ h,
                                                  ushort_t* __restrict__ hb)
{
    int e = blockIdx.x * 256 + threadIdx.x;
    if (e >= 2000 * 512) return;
    int m = e & 511;
    int row = e >> 9;
    int b = row >= 1000 ? 1 : 0;
    int t = row - b * 1000;
    float acc = bias[m];
#pragma unroll
    for (int k = 0; k < 31; k++) {
        int tt = t - 15 + k;
        if (tt >= 0 && tt < 1000)
            acc += ln[((size_t)(b * 1000 + tt)) * 512 + m] * dcwt[k * 512 + m];
    }
    float v = a[e] + acc;
    h[e] = v;
    hb[e] = f2b(v);
}

// ---------------- seq_mask output ----------------
__global__ void mask_k(const int* __restrict__ lengths, float* __restrict__ out)
{
    int i = blockIdx.x * 256 + threadIdx.x;
    if (i >= 2000) return;
    out[i] = ((i % 1000) < lengths[i / 1000]) ? 1.f : 0.f;
}

extern "C" void kernel_launch(void* const* d_in, const int* in_sizes, int n_in,
                              void* d_out, int out_size, void* d_ws, size_t ws_size,
                              hipStream_t stream)
{
    const float* x       = (const float*)d_in[0];
    const int*   lengths = (const int*)  d_in[1];
    const float* w_in0   = (const float*)d_in[2];
    const float* ln_in_g = (const float*)d_in[3];
    const float* ln_in_b = (const float*)d_in[4];
    const float* ln1_g   = (const float*)d_in[5];
    const float* ln1_b   = (const float*)d_in[6];
    const float* W_inproj= (const float*)d_in[7];
    const float* conv_w  = (const float*)d_in[8];
    const float* conv_b  = (const float*)d_in[9];
    const float* W_xproj = (const float*)d_in[10];
    const float* W_dt    = (const float*)d_in[11];
    const float* b_dt    = (const float*)d_in[12];
    const float* A_log   = (const float*)d_in[13];
    const float* Dp      = (const float*)d_in[14];
    const float* W_mo    = (const float*)d_in[15];
    const float* ln2_g   = (const float*)d_in[16];
    const float* ln2_b   = (const float*)d_in[17];
    const float* dc_w    = (const float*)d_in[18];
    const float* dc_b    = (const float*)d_in[19];
    const float* w_out   = (const float*)d_in[20];
    const float* b_out   = (const float*)d_in[21];

    char* p = (char*)d_ws;
    auto alloc_f = [&](size_t n) { float* r = (float*)p; p += n * 4; return r; };
    auto alloc_b = [&](size_t n) { ushort_t* r = (ushort_t*)p; p += n * 2; return r; };

    float* h    = alloc_f(2048 * 512);
    float* lnb  = alloc_f(2048 * 512);
    float* proj = alloc_f(2048 * 64);
    float* av   = alloc_f(2048 * 512);
    float* hloc = alloc_f(262144);
    float* sc   = alloc_f(16384);
    float* cwt  = alloc_f(4 * 4 * 1024);
    float* dcwt = alloc_f(4 * 31 * 512);
    ushort_t* xbf   = alloc_b(2048 * 288);
    ushort_t* lnbb  = alloc_b(2048 * 512);
    ushort_t* xzb   = alloc_b(2048 * 2048);
    ushort_t* xinb  = alloc_b(2048 * 1024);
    ushort_t* dtbb  = alloc_b(2048 * 1024);
    ushort_t* ysb   = alloc_b(2048 * 1024);
    ushort_t* hb    = alloc_b(2048 * 512);
    ushort_t* wt_in0 = alloc_b(512 * 288);
    ushort_t* wt_in  = alloc_b((size_t)4 * 2048 * 512);
    ushort_t* wt_dt  = alloc_b((size_t)4 * 1024 * 32);
    ushort_t* wt_mo  = alloc_b((size_t)4 * 512 * 1024);
    ushort_t* wt_out = alloc_b(576 * 512);
    ushort_t* wxb    = alloc_b((size_t)4 * 1024 * 64);
    ushort_t* wt_big = alloc_b((size_t)4 * 1152 * 1024);

    dim3 blk(256);

    // ---- weight prep ----
    cvt_x_k<<<(2000 * 288 + 255) / 256, blk, 0, stream>>>(x, xbf);
    prep_small_k<<<(16384 + 63488 + 262144 + 255) / 256, blk, 0, stream>>>(
        conv_w, dc_w, W_xproj, cwt, dcwt, wxb);
    tr_w_k<<<dim3(16, 9, 1),  blk, 0, stream>>>(w_in0, wt_in0, 257, 512, 288, 512, 0, 0);
    tr_w_k<<<dim3(64, 16, 4), blk, 0, stream>>>(W_inproj, wt_in, 512, 2048, 512, 2048,
                                                (size_t)512 * 2048, (size_t)2048 * 512);
    tr_w_k<<<dim3(32, 1, 4),  blk, 0, stream>>>(W_dt, wt_dt, 32, 1024, 32, 1024,
                                                (size_t)32 * 1024, (size_t)1024 * 32);
    tr_w_k<<<dim3(16, 32, 4), blk, 0, stream>>>(W_mo, wt_mo, 1024, 512, 1024, 512,
                                                (size_t)1024 * 512, (size_t)512 * 1024);
    tr_w_k<<<dim3(17, 16, 1), blk, 0, stream>>>(w_out, wt_out, 512, 514, 512, 514, 0, 0);
    // W_x[:,32:64] transposed into wt_big rows 1024..1055
    tr_w_k<<<dim3(1, 32, 4),  blk, 0, stream>>>(W_xproj + 32, wt_big + (size_t)1024 * 1024,
                                                1024, 32, 1024, 64,
                                                (size_t)1024 * 64, (size_t)1152 * 1024);
    // W_comb (batched over 4 layers): wt_big[j][k] = sum_r W_dt[r][j] * W_x[k][r]
    gemm5<false, 0, false, false, true><<<dim3(16, 16, 4), blk, 0, stream>>>(
        wt_dt, 32, wxb, 64, nullptr, nullptr, 0, nullptr, 0, wt_big, 1024,
        1024, 1024, 32,
        (size_t)1024 * 32, (size_t)1024 * 64, (size_t)1152 * 1024);

    // ---- input projection + LN/relu ----
    gemm5<false, 0, false, true, false><<<dim3(8, 32), blk, 0, stream>>>(
        xbf, 288, wt_in0, 288, nullptr, nullptr, 0, lnb, 512, nullptr, 0,
        2000, 512, 288, 0, 0, 0);
    ln_k<true, false><<<500, blk, 0, stream>>>(lnb, ln_in_g, ln_in_b, h, 2000);

    for (int i = 0; i < 4; i++) {
        const float* Al = A_log + (size_t)i * 16384;
        ln_k<false, true><<<500, blk, 0, stream>>>(h, ln1_g + i * 512, ln1_b + i * 512,
                                                   lnbb, 2000);
        gemm5<false, 0, false, false, true><<<dim3(32, 32), blk, 0, stream>>>(
            lnbb, 512, wt_in + (size_t)i * 2048 * 512, 512,
            nullptr, nullptr, 0, nullptr, 0, xzb, 2048, 2000, 2048, 512, 0, 0, 0);
        conv4_silu_k<<<1000, blk, 0, stream>>>(xzb, cwt + i * 4096,
                                               conv_b + i * 1024, xinb);
        // fused xproj+dt: N=1056 (1024 dt bf16 | 32 B,C f32)
        gemm5<false, 2, false, false, false><<<dim3(17, 32), blk, 0, stream>>>(
            xinb, 1024, wt_big + (size_t)i * 1152 * 1024, 1024,
            b_dt + i * 1024, proj, 64, nullptr, 0, dtbb, 1024, 2000, 1056, 1024, 0, 0, 0);
        scan_part1<<<dim3(64, NC, 2), blk, 0, stream>>>(dtbb, xinb, proj, Al, hloc, sc);
        scan_combine<<<128, blk, 0, stream>>>(Al, hloc, sc);
        scan_part2<<<dim3(64, NC, 2), blk, 0, stream>>>(dtbb, xinb, proj, Al, hloc,
                                                        Dp + i * 1024, xzb, ysb);
        gemm5<false, 0, true, true, false><<<dim3(8, 32), blk, 0, stream>>>(
            ysb, 1024, wt_mo + (size_t)i * 512 * 1024, 1024,
            nullptr, h, 512, av, 512, nullptr, 0, 2000, 512, 1024, 0, 0, 0);
        ln_k<false, false><<<500, blk, 0, stream>>>(av, ln2_g + i * 512, ln2_b + i * 512,
                                                    lnb, 2000);
        dcconv31_k<<<4000, blk, 0, stream>>>(lnb, av, dcwt + i * 31 * 512,
                                             dc_b + i * 512, h, hb);
    }

    gemm5<true, 0, false, true, false><<<dim3(9, 32), blk, 0, stream>>>(
        hb, 512, wt_out, 512, b_out, nullptr, 0, (float*)d_out, 514, nullptr, 0,
        2000, 514, 512, 0, 0, 0);
    mask_k<<<8, blk, 0, stream>>>(lengths, (float*)d_out + 2000 * 514);
}